// Round 1
// baseline (622.875 us; speedup 1.0000x reference)
//
#include <hip/hip_runtime.h>
#include <math.h>

constexpr int NT = 768;      // sequence length N
constexpr int DT = 768;      // model dim D
constexpr int HT = 16;       // heads
constexpr int HDT = 48;      // head dim
constexpr int ZDT = 128;     // pair-rep dim
constexpr int NN = NT * NT;  // 589824
constexpr float LN_EPS = 1e-5f;
constexpr float SCALE = 0.14433756729740643f;  // 48^-0.5
constexpr int KP = 72;       // LDS k-stride in bf16 elems (64 + 8 pad)

typedef __attribute__((ext_vector_type(8))) short bfrag;   // 8 bf16 (4 VGPR)
typedef __attribute__((ext_vector_type(4))) float ffrag;   // 4 fp32 acc

#define MFMA16(a, b, c) __builtin_amdgcn_mfma_f32_16x16x32_bf16(a, b, c, 0, 0, 0)

__device__ __forceinline__ short f2b(float f) {
  unsigned u = __builtin_bit_cast(unsigned, f);
  u += 0x7fffu + ((u >> 16) & 1u);   // RNE
  return (short)(u >> 16);
}
__device__ __forceinline__ float b2f(short s) {
  return __builtin_bit_cast(float, (unsigned)(unsigned short)s << 16);
}

// ---------------------------------------------------------------------------
// setup: fused  prep (blocks 0..719)  |  ln_s (720..1487)  |  zsetup (1488)
//   prep:  cast + transpose the 5 weight matrices to bf16 [n][k]
//   ln_s:  LayerNorm(s) -> bf16 snb [m][k]
//   zsetup: fold z_norm_w into z_w
// ---------------------------------------------------------------------------
__global__ __launch_bounds__(256) void setup_kernel(
    const float* __restrict__ s, const float* __restrict__ nsw,
    const float* __restrict__ nsb, short* __restrict__ snb,
    const float* __restrict__ qw, const float* __restrict__ kw,
    const float* __restrict__ vw, const float* __restrict__ gw,
    const float* __restrict__ ow, short* __restrict__ wt,
    const float* __restrict__ znw, const float* __restrict__ znb,
    const float* __restrict__ zw, float* __restrict__ w1,
    float* __restrict__ bh) {
  const int bid = blockIdx.x;
  const int t = threadIdx.x;
  if (bid < 720) {
    // ---------------- prep branch (was grid 12x12x5: x=n-tile,y=k-tile,z=which)
    __shared__ float Ts[64][65];
    const int which = bid / 144;
    const int rem = bid % 144;
    const int k0 = (rem / 12) * 64;
    const int n0 = (rem % 12) * 64;
    const float* src = which == 0 ? qw : which == 1 ? kw : which == 2 ? vw
                       : which == 3 ? gw : ow;
    short* dst = wt + (size_t)which * NN;
    const int r = t >> 4, c = (t & 15) * 4;
#pragma unroll
    for (int i = 0; i < 4; i++) {
      int rr = r + i * 16;
      float4 v = *(const float4*)&src[(size_t)(k0 + rr) * DT + n0 + c];
      Ts[rr][c + 0] = v.x; Ts[rr][c + 1] = v.y;
      Ts[rr][c + 2] = v.z; Ts[rr][c + 3] = v.w;
    }
    __syncthreads();
#pragma unroll
    for (int i = 0; i < 2; i++) {
      int cid = t + i * 256;          // 512 chunks of 8
      int nr = cid >> 3, kc = cid & 7;
      union { uint4 u; short s2[8]; } pk;
#pragma unroll
      for (int j = 0; j < 8; j++) pk.s2[j] = f2b(Ts[kc * 8 + j][nr]);
      *(uint4*)&dst[(size_t)(n0 + nr) * DT + k0 + kc * 8] = pk.u;
    }
  } else if (bid < 1488) {
    // ---------------- ln_s branch
    const int row = bid - 720;
    const float* x = s + row * DT;
    float v0 = x[t], v1 = x[t + 256], v2 = x[t + 512];
    float sum = v0 + v1 + v2;
    float sq = v0 * v0 + v1 * v1 + v2 * v2;
#pragma unroll
    for (int off = 32; off; off >>= 1) {
      sum += __shfl_xor(sum, off);
      sq += __shfl_xor(sq, off);
    }
    __shared__ float ls[4], lq[4], stats[2];
    const int wid = t >> 6;
    if ((t & 63) == 0) { ls[wid] = sum; lq[wid] = sq; }
    __syncthreads();
    if (t == 0) {
      float S = ls[0] + ls[1] + ls[2] + ls[3];
      float Q = lq[0] + lq[1] + lq[2] + lq[3];
      float mu = S * (1.f / DT);
      float var = Q * (1.f / DT) - mu * mu;
      stats[0] = mu;
      stats[1] = rsqrtf(var + LN_EPS);
    }
    __syncthreads();
    const float mu = stats[0], rs = stats[1];
    short* y = snb + row * DT;
    y[t] = f2b((v0 - mu) * rs * nsw[t] + nsb[t]);
    y[t + 256] = f2b((v1 - mu) * rs * nsw[t + 256] + nsb[t + 256]);
    y[t + 512] = f2b((v2 - mu) * rs * nsw[t + 512] + nsb[t + 512]);
  } else {
    // ---------------- zsetup branch
#pragma unroll
    for (int i = 0; i < 8; i++) {
      int idx = t * 8 + i;
      int c = idx >> 4;
      w1[idx] = znw[c] * zw[idx];
    }
    if (t < HT) {
      float sv = 0.f;
      for (int c = 0; c < ZDT; c++) sv += znb[c] * zw[c * HT + t];
      bh[t] = sv;
    }
  }
}

// ---------------------------------------------------------------------------
// fused zbias (HBM-bound) || proj (MFMA-bound) — data-independent, so the
// 144 proj blocks (dispatched first) hide entirely under the 2304-block
// zbias memory stream instead of serializing as a separate launch.
//   blocks 0..143    : q/k/v/g projections via bf16 MFMA, 128x128 tiles
//   blocks 144..2447 : z LayerNorm + (ZD->H) projection -> bf16 bias [H][N*N]
// ---------------------------------------------------------------------------
__global__ __launch_bounds__(256) void zbias_proj_kernel(
    const short* __restrict__ snb, const short* __restrict__ wt,
    const float* __restrict__ qbias, short* __restrict__ qb,
    short* __restrict__ kb, short* __restrict__ vT, short* __restrict__ gb,
    const float* __restrict__ z, const float* __restrict__ w1,
    const float* __restrict__ bh, short* __restrict__ biasb) {
  const int bid = blockIdx.x;
  const int t = threadIdx.x;
  if (bid < 144) {
    // ---------------- proj branch (was grid 6x6x4: x=N0,y=M0,z=which)
    __shared__ short As[128 * KP];
    __shared__ short Bs[128 * KP];
    const int which = bid / 36;
    const int rem = bid % 36;
    const int N0 = (rem % 6) * 128;
    const int M0 = (rem / 6) * 128;
    const short* W = wt + (size_t)which * NN;
    const int w = t >> 6, l = t & 63;
    const int wm = (w >> 1) * 64, wn = (w & 1) * 64;
    const int lane16 = l & 15, quad = l >> 4;
    ffrag acc[4][4] = {};
    const int srow = t >> 3, skc = t & 7;
    for (int k0 = 0; k0 < DT; k0 += 64) {
      uint4 av[4], bv[4];
#pragma unroll
      for (int i = 0; i < 4; i++) {
        int row = srow + i * 32;
        av[i] = *(const uint4*)&snb[(size_t)(M0 + row) * DT + k0 + skc * 8];
        bv[i] = *(const uint4*)&W[(size_t)(N0 + row) * DT + k0 + skc * 8];
      }
      __syncthreads();
#pragma unroll
      for (int i = 0; i < 4; i++) {
        int row = srow + i * 32;
        *(uint4*)&As[row * KP + skc * 8] = av[i];
        *(uint4*)&Bs[row * KP + skc * 8] = bv[i];
      }
      __syncthreads();
#pragma unroll
      for (int ks = 0; ks < 2; ks++) {
        bfrag a[4], b[4];
#pragma unroll
        for (int i = 0; i < 4; i++)
          a[i] = *(const bfrag*)&As[(wm + i * 16 + lane16) * KP + ks * 32 + quad * 8];
#pragma unroll
        for (int j = 0; j < 4; j++)
          b[j] = *(const bfrag*)&Bs[(wn + j * 16 + lane16) * KP + ks * 32 + quad * 8];
#pragma unroll
        for (int i = 0; i < 4; i++)
#pragma unroll
          for (int j = 0; j < 4; j++) acc[i][j] = MFMA16(a[i], b[j], acc[i][j]);
      }
      __syncthreads();
    }
#pragma unroll
    for (int i = 0; i < 4; i++) {
#pragma unroll
      for (int j = 0; j < 4; j++) {
        int n = N0 + wn + j * 16 + lane16;
#pragma unroll
        for (int r = 0; r < 4; r++) {
          int m = M0 + wm + i * 16 + quad * 4 + r;
          float v = acc[i][j][r];
          if (which == 0) {
            qb[(size_t)m * DT + n] = f2b(v + qbias[n]);
          } else if (which == 1) {
            kb[(size_t)m * DT + n] = f2b(v);
          } else if (which == 2) {
            vT[(size_t)n * NT + m] = f2b(v);   // [h*48+d][seq] for AV B-operand
          } else {
            gb[(size_t)m * DT + n] = f2b(1.f / (1.f + __expf(-v)));
          }
        }
      }
    }
  } else {
    // ---------------- zbias branch
    const int slot = t >> 5;
    const int hq = (t >> 3) & 3;
    const int cg = t & 7;
    const int c0 = cg * 16;
    const int h0 = hq * 4;
    float4 Wr[16];
#pragma unroll
    for (int j = 0; j < 16; j++)
      Wr[j] = *(const float4*)&w1[(c0 + j) * HT + h0];
    const float4 B4 = *(const float4*)&bh[h0];
    const int row0 = (bid - 144) * 256;
    for (int it = 0; it < 32; it++) {
      const int rid = row0 + it * 8 + slot;
      const float* zp = &z[(size_t)rid * ZDT + c0];
      float x[16];
      *(float4*)&x[0] = *(const float4*)&zp[0];
      *(float4*)&x[4] = *(const float4*)&zp[4];
      *(float4*)&x[8] = *(const float4*)&zp[8];
      *(float4*)&x[12] = *(const float4*)&zp[12];
      float sum = 0.f, sq = 0.f;
#pragma unroll
      for (int j = 0; j < 16; j++) { sum += x[j]; sq += x[j] * x[j]; }
#pragma unroll
      for (int m = 1; m <= 4; m <<= 1) {
        sum += __shfl_xor(sum, m);
        sq += __shfl_xor(sq, m);
      }
      const float mu = sum * (1.f / 128.f);
      const float rs = rsqrtf(sq * (1.f / 128.f) - mu * mu + LN_EPS);
      float ax = 0.f, ay = 0.f, az = 0.f, aw = 0.f;
#pragma unroll
      for (int j = 0; j < 16; j++) {
        float xc = x[j] - mu;
        ax += xc * Wr[j].x; ay += xc * Wr[j].y;
        az += xc * Wr[j].z; aw += xc * Wr[j].w;
      }
#pragma unroll
      for (int m = 1; m <= 4; m <<= 1) {
        ax += __shfl_xor(ax, m); ay += __shfl_xor(ay, m);
        az += __shfl_xor(az, m); aw += __shfl_xor(aw, m);
      }
      if (cg == 0) {
        biasb[(size_t)(h0 + 0) * NN + rid] = f2b(ax * rs + B4.x);
        biasb[(size_t)(h0 + 1) * NN + rid] = f2b(ay * rs + B4.y);
        biasb[(size_t)(h0 + 2) * NN + rid] = f2b(az * rs + B4.z);
        biasb[(size_t)(h0 + 3) * NN + rid] = f2b(aw * rs + B4.w);
      }
    }
  }
}

// ------- fused attention: S=QK^T*scale+bias, online softmax, O=PV
// grid (12 q-tiles of 64, 16 heads); 4 waves, wave w owns q-rows w*16..+16
__global__ __launch_bounds__(256) void attn_kernel(
    const short* __restrict__ qb, const short* __restrict__ kb,
    const short* __restrict__ vT, const short* __restrict__ biasb,
    float* __restrict__ oX) {
  __shared__ short Ks[128 * 48];       // [kpos][d]
  __shared__ short Vs[48 * 136];       // [d][kpos+8 pad]
  __shared__ short Ps[4][16 * 136];    // per-wave private P slice
  const int t = threadIdx.x;
  const int h = blockIdx.y;
  const int q0 = blockIdx.x * 64;
  const int w = t >> 6, l = t & 63;
  const int lane16 = l & 15, quad = l >> 4;
  // Q A-frags (A[m=lane16][k=quad*8+j]) live in registers for the whole kernel
  const int qrow = q0 + w * 16 + lane16;
  bfrag a_q0 = *(const bfrag*)&qb[(size_t)qrow * DT + h * HDT + quad * 8];
  bfrag a_q1 = {0, 0, 0, 0, 0, 0, 0, 0};   // k 48..63 zero-padded
  if (quad < 2)
    a_q1 = *(const bfrag*)&qb[(size_t)qrow * DT + h * HDT + 32 + quad * 8];
  // FIX(r3->r4): quad>=2 lanes must NOT read past the 48-short K row (row 127
  // overran the Ks allocation -> uninitialized LDS -> 0*NaN=NaN). Their A-frag
  // is zero, so clamp them to a safe in-row address instead.
  const int koff1 = (quad < 2) ? (32 + quad * 8) : 0;
  ffrag acc_o[3] = {};
  float m_run[4] = {-1e30f, -1e30f, -1e30f, -1e30f};
  float l_run[4] = {};
  const size_t bias_base =
      (size_t)h * NN + (size_t)(q0 + w * 16 + quad * 4) * NT + lane16;
  for (int kt = 0; kt < 6; kt++) {
    const int k0 = kt * 128;
    uint4 kv[3], vv[3];
#pragma unroll
    for (int i = 0; i < 3; i++) {
      int cid = t + i * 256;
      int kr = cid / 6, kc = cid % 6;
      kv[i] = *(const uint4*)&kb[(size_t)(k0 + kr) * DT + h * HDT + kc * 8];
      int vr = cid >> 4, vc = cid & 15;
      vv[i] = *(const uint4*)&vT[((size_t)h * HDT + vr) * NT + k0 + vc * 8];
    }
    short bias_s[8][4];
#pragma unroll
    for (int j = 0; j < 8; j++)
#pragma unroll
      for (int r = 0; r < 4; r++)
        bias_s[j][r] = biasb[bias_base + (size_t)r * NT + k0 + j * 16];
    __syncthreads();
#pragma unroll
    for (int i = 0; i < 3; i++) {
      int cid = t + i * 256;
      int kr = cid / 6, kc = cid % 6;
      *(uint4*)&Ks[kr * 48 + kc * 8] = kv[i];
      int vr = cid >> 4, vc = cid & 15;
      *(uint4*)&Vs[vr * 136 + vc * 8] = vv[i];
    }
    __syncthreads();
    // S = Q K^T   (8 n-tiles x 2 k-steps)
    ffrag sc[8];
#pragma unroll
    for (int j = 0; j < 8; j++) {
      ffrag zf = {0.f, 0.f, 0.f, 0.f};
      bfrag b0 = *(const bfrag*)&Ks[(j * 16 + lane16) * 48 + quad * 8];
      bfrag b1 = *(const bfrag*)&Ks[(j * 16 + lane16) * 48 + koff1];
      zf = MFMA16(a_q0, b0, zf);
      sc[j] = MFMA16(a_q1, b1, zf);
    }
    // logits + online softmax (C layout: col=lane16, row=quad*4+r)
    float li[8][4];
#pragma unroll
    for (int j = 0; j < 8; j++)
#pragma unroll
      for (int r = 0; r < 4; r++)
        li[j][r] = sc[j][r] * SCALE + b2f(bias_s[j][r]);
    float alpha[4];
#pragma unroll
    for (int r = 0; r < 4; r++) {
      float m = li[0][r];
#pragma unroll
      for (int j = 1; j < 8; j++) m = fmaxf(m, li[j][r]);
#pragma unroll
      for (int k = 1; k <= 8; k <<= 1) m = fmaxf(m, __shfl_xor(m, k));
      float mn = fmaxf(m_run[r], m);
      alpha[r] = __expf(m_run[r] - mn);
      m_run[r] = mn;
    }
#pragma unroll
    for (int j = 0; j < 8; j++)
#pragma unroll
      for (int r = 0; r < 4; r++) li[j][r] = __expf(li[j][r] - m_run[r]);
#pragma unroll
    for (int r = 0; r < 4; r++) {
      float ssum = li[0][r];
#pragma unroll
      for (int j = 1; j < 8; j++) ssum += li[j][r];
#pragma unroll
      for (int k = 1; k <= 8; k <<= 1) ssum += __shfl_xor(ssum, k);
      l_run[r] = l_run[r] * alpha[r] + ssum;
    }
#pragma unroll
    for (int dt = 0; dt < 3; dt++)
#pragma unroll
      for (int r = 0; r < 4; r++) acc_o[dt][r] *= alpha[r];
    // P -> per-wave LDS slice (C layout -> A layout); same-wave RAW is safe:
    // LDS ops from one wave execute in order (DS pipe FIFO per wave)
#pragma unroll
    for (int j = 0; j < 8; j++)
#pragma unroll
      for (int r = 0; r < 4; r++)
        Ps[w][(quad * 4 + r) * 136 + j * 16 + lane16] = f2b(li[j][r]);
    // O += P V   (3 d-tiles x 4 k-steps)
#pragma unroll
    for (int ks = 0; ks < 4; ks++) {
      bfrag ap = *(const bfrag*)&Ps[w][lane16 * 136 + ks * 32 + quad * 8];
#pragma unroll
      for (int dt = 0; dt < 3; dt++) {
        bfrag bv = *(const bfrag*)&Vs[(dt * 16 + lane16) * 136 + ks * 32 + quad * 8];
        acc_o[dt] = MFMA16(ap, bv, acc_o[dt]);
      }
    }
  }
  float inv[4];
#pragma unroll
  for (int r = 0; r < 4; r++) inv[r] = 1.f / l_run[r];
#pragma unroll
  for (int dt = 0; dt < 3; dt++)
#pragma unroll
    for (int r = 0; r < 4; r++)
      oX[(size_t)(q0 + w * 16 + quad * 4 + r) * DT + h * HDT + dt * 16 + lane16] =
          acc_o[dt][r] * inv[r];
}

// ---------------------------- out = (o .* g) @ o_w via bf16 MFMA
// retiled 128x128(36 blocks, 14% CU coverage) -> 64x64(144 blocks): the
// per-block critical path (12 k-steps) stages quarter-size tiles and 4x more
// CUs participate. k-accumulation order per output element is unchanged.
__global__ __launch_bounds__(256) void outproj_kernel(
    const float* __restrict__ oX, const short* __restrict__ gb,
    const short* __restrict__ owt, float* __restrict__ out) {
  __shared__ short As[64 * KP];
  __shared__ short Bs[64 * KP];
  const int t = threadIdx.x;
  const int N0 = blockIdx.x * 64;
  const int M0 = blockIdx.y * 64;
  const int w = t >> 6, l = t & 63;
  const int wm = (w >> 1) * 32, wn = (w & 1) * 32;
  const int lane16 = l & 15, quad = l >> 4;
  ffrag acc[2][2] = {};
  const int srow = t >> 2;          // 0..63
  const int sc = (t & 3) * 16;      // elem offset 0/16/32/48
  for (int k0 = 0; k0 < DT; k0 += 64) {
    uint4 apk[2], bvv[2];
    const float* op = &oX[(size_t)(M0 + srow) * DT + k0 + sc];
    const short* gp = &gb[(size_t)(M0 + srow) * DT + k0 + sc];
    const short* bp = &owt[(size_t)(N0 + srow) * DT + k0 + sc];
#pragma unroll
    for (int i = 0; i < 2; i++) {
      float4 o0 = *(const float4*)&op[i * 8 + 0];
      float4 o1 = *(const float4*)&op[i * 8 + 4];
      union { uint4 u; short s2[8]; } gv;
      gv.u = *(const uint4*)&gp[i * 8];
      union { uint4 u; short s2[8]; } pk;
      float go[8] = {o0.x, o0.y, o0.z, o0.w, o1.x, o1.y, o1.z, o1.w};
#pragma unroll
      for (int jj = 0; jj < 8; jj++) pk.s2[jj] = f2b(go[jj] * b2f(gv.s2[jj]));
      apk[i] = pk.u;
      bvv[i] = *(const uint4*)&bp[i * 8];
    }
    __syncthreads();
    *(uint4*)&As[srow * KP + sc] = apk[0];
    *(uint4*)&As[srow * KP + sc + 8] = apk[1];
    *(uint4*)&Bs[srow * KP + sc] = bvv[0];
    *(uint4*)&Bs[srow * KP + sc + 8] = bvv[1];
    __syncthreads();
#pragma unroll
    for (int ks = 0; ks < 2; ks++) {
      bfrag a[2], b[2];
#pragma unroll
      for (int i = 0; i < 2; i++)
        a[i] = *(const bfrag*)&As[(wm + i * 16 + lane16) * KP + ks * 32 + quad * 8];
#pragma unroll
      for (int j = 0; j < 2; j++)
        b[j] = *(const bfrag*)&Bs[(wn + j * 16 + lane16) * KP + ks * 32 + quad * 8];
#pragma unroll
      for (int i = 0; i < 2; i++)
#pragma unroll
        for (int j = 0; j < 2; j++) acc[i][j] = MFMA16(a[i], b[j], acc[i][j]);
    }
  }
#pragma unroll
  for (int i = 0; i < 2; i++)
#pragma unroll
    for (int j = 0; j < 2; j++) {
      int n = N0 + wn + j * 16 + lane16;
#pragma unroll
      for (int r = 0; r < 4; r++) {
        int m = M0 + wm + i * 16 + quad * 4 + r;
        out[(size_t)m * DT + n] = acc[i][j][r];
      }
    }
}

extern "C" void kernel_launch(void* const* d_in, const int* in_sizes, int n_in,
                              void* d_out, int out_size, void* d_ws,
                              size_t ws_size, hipStream_t stream) {
  const float* s = (const float*)d_in[0];
  const float* z = (const float*)d_in[1];
  const float* nsw = (const float*)d_in[2];
  const float* nsb = (const float*)d_in[3];
  const float* qw = (const float*)d_in[4];
  const float* qbias = (const float*)d_in[5];
  const float* kw = (const float*)d_in[6];
  const float* vw = (const float*)d_in[7];
  const float* gw = (const float*)d_in[8];
  const float* znw = (const float*)d_in[9];
  const float* znb = (const float*)d_in[10];
  const float* zww = (const float*)d_in[11];
  const float* ow = (const float*)d_in[12];
  float* out = (float*)d_out;
  char* W = (char*)d_ws;

  short* biasb = (short*)W;                        // 18,874,368 B
  short* snb = (short*)(W + 18874368);             // 1,179,648 B
  short* qb = (short*)(W + 20054016);
  short* kb = (short*)(W + 21233664);
  short* gb = (short*)(W + 22413312);
  short* vT = (short*)(W + 23592960);
  short* wt = (short*)(W + 24772608);              // 5 x 1,179,648 B
  float* oX = (float*)(W + 30670848);              // 2,359,296 B
  float* w1 = (float*)(W + 33030144);              // 8 KB
  float* bh = (float*)(W + 33038336);

  // 4 launches (was 7): setup -> (zbias || proj) -> attn -> outproj
  setup_kernel<<<1489, 256, 0, stream>>>(s, nsw, nsb, snb, qw, kw, vw, gw, ow,
                                         wt, znw, znb, zww, w1, bh);
  zbias_proj_kernel<<<2448, 256, 0, stream>>>(snb, wt, qbias, qb, kb, vT, gb,
                                              z, w1, bh, biasb);
  attn_kernel<<<dim3(12, 16), 256, 0, stream>>>(qb, kb, vT, biasb, oX);
  outproj_kernel<<<dim3(12, 12), 256, 0, stream>>>(oX, gb, wt + 4 * (size_t)NN,
                                                   out);
}

// Round 2
// 589.760 us; speedup vs baseline: 1.0561x; 1.0561x over previous
//
#include <hip/hip_runtime.h>
#include <math.h>

constexpr int NT = 768;      // sequence length N
constexpr int DT = 768;      // model dim D
constexpr int HT = 16;       // heads
constexpr int HDT = 48;      // head dim
constexpr int ZDT = 128;     // pair-rep dim
constexpr int NN = NT * NT;  // 589824
constexpr float LN_EPS = 1e-5f;
constexpr float SCALE = 0.14433756729740643f;  // 48^-0.5
constexpr int KP = 72;       // LDS k-stride in bf16 elems (64 + 8 pad)

typedef __attribute__((ext_vector_type(8))) short bfrag;   // 8 bf16 (4 VGPR)
typedef __attribute__((ext_vector_type(4))) float ffrag;   // 4 fp32 acc

#define MFMA16(a, b, c) __builtin_amdgcn_mfma_f32_16x16x32_bf16(a, b, c, 0, 0, 0)

__device__ __forceinline__ short f2b(float f) {
  unsigned u = __builtin_bit_cast(unsigned, f);
  u += 0x7fffu + ((u >> 16) & 1u);   // RNE
  return (short)(u >> 16);
}
__device__ __forceinline__ float b2f(short s) {
  return __builtin_bit_cast(float, (unsigned)(unsigned short)s << 16);
}

// ---------------------------------------------------------------------------
// setup: fused  prep (blocks 0..719)  |  ln_s (720..1487)  |  zsetup (1488)
//   prep:  cast + transpose the 5 weight matrices to bf16 [n][k]
//   ln_s:  LayerNorm(s) -> bf16 snb [m][k]
//   zsetup: fold z_norm_w into z_w; emit W^T hi/lo bf16 + colsums for the
//           MFMA-based zbias kernel
// ---------------------------------------------------------------------------
__global__ __launch_bounds__(256) void setup_kernel(
    const float* __restrict__ s, const float* __restrict__ nsw,
    const float* __restrict__ nsb, short* __restrict__ snb,
    const float* __restrict__ qw, const float* __restrict__ kw,
    const float* __restrict__ vw, const float* __restrict__ gw,
    const float* __restrict__ ow, short* __restrict__ wt,
    const float* __restrict__ znw, const float* __restrict__ znb,
    const float* __restrict__ zw, short* __restrict__ w1th,
    short* __restrict__ w1tl, float* __restrict__ wcs,
    float* __restrict__ bh) {
  const int bid = blockIdx.x;
  const int t = threadIdx.x;
  if (bid < 720) {
    // ---------------- prep branch (x=n-tile, y=k-tile, z=which flattened)
    __shared__ float Ts[64][65];
    const int which = bid / 144;
    const int rem = bid % 144;
    const int k0 = (rem / 12) * 64;
    const int n0 = (rem % 12) * 64;
    const float* src = which == 0 ? qw : which == 1 ? kw : which == 2 ? vw
                       : which == 3 ? gw : ow;
    short* dst = wt + (size_t)which * NN;
    const int r = t >> 4, c = (t & 15) * 4;
#pragma unroll
    for (int i = 0; i < 4; i++) {
      int rr = r + i * 16;
      float4 v = *(const float4*)&src[(size_t)(k0 + rr) * DT + n0 + c];
      Ts[rr][c + 0] = v.x; Ts[rr][c + 1] = v.y;
      Ts[rr][c + 2] = v.z; Ts[rr][c + 3] = v.w;
    }
    __syncthreads();
#pragma unroll
    for (int i = 0; i < 2; i++) {
      int cid = t + i * 256;          // 512 chunks of 8
      int nr = cid >> 3, kc = cid & 7;
      union { uint4 u; short s2[8]; } pk;
#pragma unroll
      for (int j = 0; j < 8; j++) pk.s2[j] = f2b(Ts[kc * 8 + j][nr]);
      *(uint4*)&dst[(size_t)(n0 + nr) * DT + k0 + kc * 8] = pk.u;
    }
  } else if (bid < 1488) {
    // ---------------- ln_s branch
    const int row = bid - 720;
    const float* x = s + row * DT;
    float v0 = x[t], v1 = x[t + 256], v2 = x[t + 512];
    float sum = v0 + v1 + v2;
    float sq = v0 * v0 + v1 * v1 + v2 * v2;
#pragma unroll
    for (int off = 32; off; off >>= 1) {
      sum += __shfl_xor(sum, off);
      sq += __shfl_xor(sq, off);
    }
    __shared__ float ls[4], lq[4], stats[2];
    const int wid = t >> 6;
    if ((t & 63) == 0) { ls[wid] = sum; lq[wid] = sq; }
    __syncthreads();
    if (t == 0) {
      float S = ls[0] + ls[1] + ls[2] + ls[3];
      float Q = lq[0] + lq[1] + lq[2] + lq[3];
      float mu = S * (1.f / DT);
      float var = Q * (1.f / DT) - mu * mu;
      stats[0] = mu;
      stats[1] = rsqrtf(var + LN_EPS);
    }
    __syncthreads();
    const float mu = stats[0], rs = stats[1];
    short* y = snb + row * DT;
    y[t] = f2b((v0 - mu) * rs * nsw[t] + nsb[t]);
    y[t + 256] = f2b((v1 - mu) * rs * nsw[t + 256] + nsb[t + 256]);
    y[t + 512] = f2b((v2 - mu) * rs * nsw[t + 512] + nsb[t + 512]);
  } else {
    // ---------------- zsetup branch
    __shared__ float sm[ZDT * HT];     // w1[c][h] = znw[c] * zw[c][h]
#pragma unroll
    for (int i = 0; i < 8; i++) {
      int idx = t * 8 + i;
      int c = idx >> 4;
      sm[idx] = znw[c] * zw[idx];
    }
    __syncthreads();
#pragma unroll
    for (int i = 0; i < 8; i++) {
      int idx = t * 8 + i;
      int c = idx >> 4, h = idx & 15;
      float v = sm[idx];
      short hi = f2b(v);
      w1th[h * ZDT + c] = hi;                 // W^T hi (bf16)
      w1tl[h * ZDT + c] = f2b(v - b2f(hi));   // W^T lo residual (bf16)
    }
    if (t < HT) {
      float s1 = 0.f, s2 = 0.f;
      for (int c = 0; c < ZDT; c++) s1 += sm[c * HT + t];
      wcs[t] = s1;                            // column sums of w1
      for (int c = 0; c < ZDT; c++) s2 += znb[c] * zw[c * HT + t];
      bh[t] = s2;                             // folded LN bias term
    }
  }
}

// ------------------------------- q/k/v/g projections via bf16 MFMA, 128x128
__global__ __launch_bounds__(256) void proj_kernel(
    const short* __restrict__ snb, const short* __restrict__ wt,
    const float* __restrict__ qbias, short* __restrict__ qb,
    short* __restrict__ kb, short* __restrict__ vT, short* __restrict__ gb) {
  __shared__ short As[128 * KP];
  __shared__ short Bs[128 * KP];
  const int t = threadIdx.x;
  const int which = blockIdx.z;
  const short* W = wt + (size_t)which * NN;
  const int N0 = blockIdx.x * 128;
  const int M0 = blockIdx.y * 128;
  const int w = t >> 6, l = t & 63;
  const int wm = (w >> 1) * 64, wn = (w & 1) * 64;
  const int lane16 = l & 15, quad = l >> 4;
  ffrag acc[4][4] = {};
  const int srow = t >> 3, skc = t & 7;
  for (int k0 = 0; k0 < DT; k0 += 64) {
    uint4 av[4], bv[4];
#pragma unroll
    for (int i = 0; i < 4; i++) {
      int row = srow + i * 32;
      av[i] = *(const uint4*)&snb[(size_t)(M0 + row) * DT + k0 + skc * 8];
      bv[i] = *(const uint4*)&W[(size_t)(N0 + row) * DT + k0 + skc * 8];
    }
    __syncthreads();
#pragma unroll
    for (int i = 0; i < 4; i++) {
      int row = srow + i * 32;
      *(uint4*)&As[row * KP + skc * 8] = av[i];
      *(uint4*)&Bs[row * KP + skc * 8] = bv[i];
    }
    __syncthreads();
#pragma unroll
    for (int ks = 0; ks < 2; ks++) {
      bfrag a[4], b[4];
#pragma unroll
      for (int i = 0; i < 4; i++)
        a[i] = *(const bfrag*)&As[(wm + i * 16 + lane16) * KP + ks * 32 + quad * 8];
#pragma unroll
      for (int j = 0; j < 4; j++)
        b[j] = *(const bfrag*)&Bs[(wn + j * 16 + lane16) * KP + ks * 32 + quad * 8];
#pragma unroll
      for (int i = 0; i < 4; i++)
#pragma unroll
        for (int j = 0; j < 4; j++) acc[i][j] = MFMA16(a[i], b[j], acc[i][j]);
    }
    __syncthreads();
  }
#pragma unroll
  for (int i = 0; i < 4; i++) {
#pragma unroll
    for (int j = 0; j < 4; j++) {
      int n = N0 + wn + j * 16 + lane16;
#pragma unroll
      for (int r = 0; r < 4; r++) {
        int m = M0 + wm + i * 16 + quad * 4 + r;
        float v = acc[i][j][r];
        if (which == 0) {
          qb[(size_t)m * DT + n] = f2b(v + qbias[n]);
        } else if (which == 1) {
          kb[(size_t)m * DT + n] = f2b(v);
        } else if (which == 2) {
          vT[(size_t)n * NT + m] = f2b(v);   // [h*48+d][seq] for AV B-operand
        } else {
          gb[(size_t)m * DT + n] = f2b(1.f / (1.f + __expf(-v)));
        }
      }
    }
  }
}

// ---------------------------------------------------------------------------
// zbias via MFMA: bias[rid][h] = rs*(z[rid,:]@w1[:,h] - mu*colsum(w1)[h]) + bh
// LN hoisted out of the dot; raw z feeds the MFMA A-operand as a hi/lo bf16
// split (3 MFMAs: xh*Wh + xl*Wh + xh*Wl) so precision stays ~fp32.
// One wave = one 16-row tile per iter: lane16=row, quad=k-chunk -> the MFMA
// A-frag layout, so loads are 128 B contiguous per row with zero duplication.
// grid 1152 x 512 rows; ~90 VGPR -> 5 waves/SIMD, all blocks co-resident.
// ---------------------------------------------------------------------------
__global__ __launch_bounds__(256) void zbias_kernel(
    const float* __restrict__ z, const short* __restrict__ w1th,
    const short* __restrict__ w1tl, const float* __restrict__ wcs,
    const float* __restrict__ bh, short* __restrict__ biasb) {
  const int t = threadIdx.x;
  const int w = t >> 6, l = t & 63;
  const int lane16 = l & 15, quad = l >> 4;
  // loop-invariant B-frags: W^T[h=lane16][k], hi/lo, 4 k-steps (16 VGPR)
  bfrag wb_hi[4], wb_lo[4];
#pragma unroll
  for (int ks = 0; ks < 4; ks++) {
    wb_hi[ks] = *(const bfrag*)&w1th[lane16 * ZDT + ks * 32 + quad * 8];
    wb_lo[ks] = *(const bfrag*)&w1tl[lane16 * ZDT + ks * 32 + quad * 8];
  }
  const float wcs_h = wcs[lane16];
  const float bh_h = bh[lane16];
  const int row_base0 = blockIdx.x * 512 + w * 128;
  for (int it = 0; it < 8; it++) {
    const int rbase = row_base0 + it * 16;
    const int row = rbase + lane16;
    float x[4][8];
#pragma unroll
    for (int ks = 0; ks < 4; ks++) {
      const float* zp = &z[(size_t)row * ZDT + ks * 32 + quad * 8];
      *(float4*)&x[ks][0] = *(const float4*)&zp[0];
      *(float4*)&x[ks][4] = *(const float4*)&zp[4];
    }
    // row stats (lane covers 32 of 128 elems; reduce across the 4 quads)
    float sum = 0.f, sq = 0.f;
#pragma unroll
    for (int ks = 0; ks < 4; ks++)
#pragma unroll
      for (int j = 0; j < 8; j++) {
        sum += x[ks][j];
        sq += x[ks][j] * x[ks][j];
      }
    sum += __shfl_xor(sum, 16); sq += __shfl_xor(sq, 16);
    sum += __shfl_xor(sum, 32); sq += __shfl_xor(sq, 32);
    // hi/lo split + 3-term MFMA accumulation
    ffrag acc = {0.f, 0.f, 0.f, 0.f};
#pragma unroll
    for (int ks = 0; ks < 4; ks++) {
      bfrag xh, xl;
#pragma unroll
      for (int j = 0; j < 8; j++) {
        short hi = f2b(x[ks][j]);
        xh[j] = hi;
        xl[j] = f2b(x[ks][j] - b2f(hi));
      }
      acc = MFMA16(xh, wb_hi[ks], acc);
      acc = MFMA16(xl, wb_hi[ks], acc);
      acc = MFMA16(xh, wb_lo[ks], acc);
    }
    // epilogue: C[row=quad*4+r][h=lane16]; fetch that row's stats by shuffle
    union { uint2 u; short s4[4]; } pk;
#pragma unroll
    for (int r = 0; r < 4; r++) {
      float rsum = __shfl(sum, quad * 4 + r);
      float rsq = __shfl(sq, quad * 4 + r);
      float mu = rsum * (1.f / 128.f);
      float rs = rsqrtf(rsq * (1.f / 128.f) - mu * mu + LN_EPS);
      pk.s4[r] = f2b(rs * (acc[r] - mu * wcs_h) + bh_h);
    }
    // 4 consecutive rids per lane -> one 8 B store, 32 B/wave per head stream
    *(uint2*)&biasb[(size_t)lane16 * NN + rbase + quad * 4] = pk.u;
  }
}

// ------- fused attention: S=QK^T*scale+bias, online softmax, O=PV
// grid (12 q-tiles of 64, 16 heads); 4 waves, wave w owns q-rows w*16..+16
__global__ __launch_bounds__(256) void attn_kernel(
    const short* __restrict__ qb, const short* __restrict__ kb,
    const short* __restrict__ vT, const short* __restrict__ biasb,
    float* __restrict__ oX) {
  __shared__ short Ks[128 * 48];       // [kpos][d]
  __shared__ short Vs[48 * 136];       // [d][kpos+8 pad]
  __shared__ short Ps[4][16 * 136];    // per-wave private P slice
  const int t = threadIdx.x;
  const int h = blockIdx.y;
  const int q0 = blockIdx.x * 64;
  const int w = t >> 6, l = t & 63;
  const int lane16 = l & 15, quad = l >> 4;
  const int qrow = q0 + w * 16 + lane16;
  bfrag a_q0 = *(const bfrag*)&qb[(size_t)qrow * DT + h * HDT + quad * 8];
  bfrag a_q1 = {0, 0, 0, 0, 0, 0, 0, 0};   // k 48..63 zero-padded
  if (quad < 2)
    a_q1 = *(const bfrag*)&qb[(size_t)qrow * DT + h * HDT + 32 + quad * 8];
  const int koff1 = (quad < 2) ? (32 + quad * 8) : 0;
  ffrag acc_o[3] = {};
  float m_run[4] = {-1e30f, -1e30f, -1e30f, -1e30f};
  float l_run[4] = {};
  const size_t bias_base =
      (size_t)h * NN + (size_t)(q0 + w * 16 + quad * 4) * NT + lane16;
  for (int kt = 0; kt < 6; kt++) {
    const int k0 = kt * 128;
    uint4 kv[3], vv[3];
#pragma unroll
    for (int i = 0; i < 3; i++) {
      int cid = t + i * 256;
      int kr = cid / 6, kc = cid % 6;
      kv[i] = *(const uint4*)&kb[(size_t)(k0 + kr) * DT + h * HDT + kc * 8];
      int vr = cid >> 4, vc = cid & 15;
      vv[i] = *(const uint4*)&vT[((size_t)h * HDT + vr) * NT + k0 + vc * 8];
    }
    short bias_s[8][4];
#pragma unroll
    for (int j = 0; j < 8; j++)
#pragma unroll
      for (int r = 0; r < 4; r++)
        bias_s[j][r] = biasb[bias_base + (size_t)r * NT + k0 + j * 16];
    __syncthreads();
#pragma unroll
    for (int i = 0; i < 3; i++) {
      int cid = t + i * 256;
      int kr = cid / 6, kc = cid % 6;
      *(uint4*)&Ks[kr * 48 + kc * 8] = kv[i];
      int vr = cid >> 4, vc = cid & 15;
      *(uint4*)&Vs[vr * 136 + vc * 8] = vv[i];
    }
    __syncthreads();
    // S = Q K^T   (8 n-tiles x 2 k-steps)
    ffrag sc[8];
#pragma unroll
    for (int j = 0; j < 8; j++) {
      ffrag zf = {0.f, 0.f, 0.f, 0.f};
      bfrag b0 = *(const bfrag*)&Ks[(j * 16 + lane16) * 48 + quad * 8];
      bfrag b1 = *(const bfrag*)&Ks[(j * 16 + lane16) * 48 + koff1];
      zf = MFMA16(a_q0, b0, zf);
      sc[j] = MFMA16(a_q1, b1, zf);
    }
    // logits + online softmax (C layout: col=lane16, row=quad*4+r)
    float li[8][4];
#pragma unroll
    for (int j = 0; j < 8; j++)
#pragma unroll
      for (int r = 0; r < 4; r++)
        li[j][r] = sc[j][r] * SCALE + b2f(bias_s[j][r]);
    float alpha[4];
#pragma unroll
    for (int r = 0; r < 4; r++) {
      float m = li[0][r];
#pragma unroll
      for (int j = 1; j < 8; j++) m = fmaxf(m, li[j][r]);
#pragma unroll
      for (int k = 1; k <= 8; k <<= 1) m = fmaxf(m, __shfl_xor(m, k));
      float mn = fmaxf(m_run[r], m);
      alpha[r] = __expf(m_run[r] - mn);
      m_run[r] = mn;
    }
#pragma unroll
    for (int j = 0; j < 8; j++)
#pragma unroll
      for (int r = 0; r < 4; r++) li[j][r] = __expf(li[j][r] - m_run[r]);
#pragma unroll
    for (int r = 0; r < 4; r++) {
      float ssum = li[0][r];
#pragma unroll
      for (int j = 1; j < 8; j++) ssum += li[j][r];
#pragma unroll
      for (int k = 1; k <= 8; k <<= 1) ssum += __shfl_xor(ssum, k);
      l_run[r] = l_run[r] * alpha[r] + ssum;
    }
#pragma unroll
    for (int dt = 0; dt < 3; dt++)
#pragma unroll
      for (int r = 0; r < 4; r++) acc_o[dt][r] *= alpha[r];
#pragma unroll
    for (int j = 0; j < 8; j++)
#pragma unroll
      for (int r = 0; r < 4; r++)
        Ps[w][(quad * 4 + r) * 136 + j * 16 + lane16] = f2b(li[j][r]);
    // O += P V   (3 d-tiles x 4 k-steps)
#pragma unroll
    for (int ks = 0; ks < 4; ks++) {
      bfrag ap = *(const bfrag*)&Ps[w][lane16 * 136 + ks * 32 + quad * 8];
#pragma unroll
      for (int dt = 0; dt < 3; dt++) {
        bfrag bv = *(const bfrag*)&Vs[(dt * 16 + lane16) * 136 + ks * 32 + quad * 8];
        acc_o[dt] = MFMA16(ap, bv, acc_o[dt]);
      }
    }
  }
  float inv[4];
#pragma unroll
  for (int r = 0; r < 4; r++) inv[r] = 1.f / l_run[r];
#pragma unroll
  for (int dt = 0; dt < 3; dt++)
#pragma unroll
    for (int r = 0; r < 4; r++)
      oX[(size_t)(q0 + w * 16 + quad * 4 + r) * DT + h * HDT + dt * 16 + lane16] =
          acc_o[dt][r] * inv[r];
}

// ---------------------------- out = (o .* g) @ o_w via bf16 MFMA, 64x64 tiles
__global__ __launch_bounds__(256) void outproj_kernel(
    const float* __restrict__ oX, const short* __restrict__ gb,
    const short* __restrict__ owt, float* __restrict__ out) {
  __shared__ short As[64 * KP];
  __shared__ short Bs[64 * KP];
  const int t = threadIdx.x;
  const int N0 = blockIdx.x * 64;
  const int M0 = blockIdx.y * 64;
  const int w = t >> 6, l = t & 63;
  const int wm = (w >> 1) * 32, wn = (w & 1) * 32;
  const int lane16 = l & 15, quad = l >> 4;
  ffrag acc[2][2] = {};
  const int srow = t >> 2;          // 0..63
  const int sc = (t & 3) * 16;      // elem offset 0/16/32/48
  for (int k0 = 0; k0 < DT; k0 += 64) {
    uint4 apk[2], bvv[2];
    const float* op = &oX[(size_t)(M0 + srow) * DT + k0 + sc];
    const short* gp = &gb[(size_t)(M0 + srow) * DT + k0 + sc];
    const short* bp = &owt[(size_t)(N0 + srow) * DT + k0 + sc];
#pragma unroll
    for (int i = 0; i < 2; i++) {
      float4 o0 = *(const float4*)&op[i * 8 + 0];
      float4 o1 = *(const float4*)&op[i * 8 + 4];
      union { uint4 u; short s2[8]; } gv;
      gv.u = *(const uint4*)&gp[i * 8];
      union { uint4 u; short s2[8]; } pk;
      float go[8] = {o0.x, o0.y, o0.z, o0.w, o1.x, o1.y, o1.z, o1.w};
#pragma unroll
      for (int jj = 0; jj < 8; jj++) pk.s2[jj] = f2b(go[jj] * b2f(gv.s2[jj]));
      apk[i] = pk.u;
      bvv[i] = *(const uint4*)&bp[i * 8];
    }
    __syncthreads();
    *(uint4*)&As[srow * KP + sc] = apk[0];
    *(uint4*)&As[srow * KP + sc + 8] = apk[1];
    *(uint4*)&Bs[srow * KP + sc] = bvv[0];
    *(uint4*)&Bs[srow * KP + sc + 8] = bvv[1];
    __syncthreads();
#pragma unroll
    for (int ks = 0; ks < 2; ks++) {
      bfrag a[2], b[2];
#pragma unroll
      for (int i = 0; i < 2; i++)
        a[i] = *(const bfrag*)&As[(wm + i * 16 + lane16) * KP + ks * 32 + quad * 8];
#pragma unroll
      for (int j = 0; j < 2; j++)
        b[j] = *(const bfrag*)&Bs[(wn + j * 16 + lane16) * KP + ks * 32 + quad * 8];
#pragma unroll
      for (int i = 0; i < 2; i++)
#pragma unroll
        for (int j = 0; j < 2; j++) acc[i][j] = MFMA16(a[i], b[j], acc[i][j]);
    }
  }
#pragma unroll
  for (int i = 0; i < 2; i++)
#pragma unroll
    for (int j = 0; j < 2; j++) {
      int n = N0 + wn + j * 16 + lane16;
#pragma unroll
      for (int r = 0; r < 4; r++) {
        int m = M0 + wm + i * 16 + quad * 4 + r;
        out[(size_t)m * DT + n] = acc[i][j][r];
      }
    }
}

extern "C" void kernel_launch(void* const* d_in, const int* in_sizes, int n_in,
                              void* d_out, int out_size, void* d_ws,
                              size_t ws_size, hipStream_t stream) {
  const float* s = (const float*)d_in[0];
  const float* z = (const float*)d_in[1];
  const float* nsw = (const float*)d_in[2];
  const float* nsb = (const float*)d_in[3];
  const float* qw = (const float*)d_in[4];
  const float* qbias = (const float*)d_in[5];
  const float* kw = (const float*)d_in[6];
  const float* vw = (const float*)d_in[7];
  const float* gw = (const float*)d_in[8];
  const float* znw = (const float*)d_in[9];
  const float* znb = (const float*)d_in[10];
  const float* zww = (const float*)d_in[11];
  const float* ow = (const float*)d_in[12];
  float* out = (float*)d_out;
  char* W = (char*)d_ws;

  short* biasb = (short*)W;                        // 18,874,368 B
  short* snb = (short*)(W + 18874368);             // 1,179,648 B
  short* qb = (short*)(W + 20054016);
  short* kb = (short*)(W + 21233664);
  short* gb = (short*)(W + 22413312);
  short* vT = (short*)(W + 23592960);
  short* wt = (short*)(W + 24772608);              // 5 x 1,179,648 B
  float* oX = (float*)(W + 30670848);              // 2,359,296 B
  short* w1th = (short*)(W + 33030144);            // 4096 B
  short* w1tl = (short*)(W + 33034240);            // 4096 B
  float* wcs = (float*)(W + 33038336);             // 64 B
  float* bh = (float*)(W + 33038400);              // 64 B

  // setup -> proj -> zbias(MFMA) -> attn -> outproj
  setup_kernel<<<1489, 256, 0, stream>>>(s, nsw, nsb, snb, qw, kw, vw, gw, ow,
                                         wt, znw, znb, zww, w1th, w1tl, wcs,
                                         bh);
  proj_kernel<<<dim3(6, 6, 4), 256, 0, stream>>>(snb, wt, qbias, qb, kb, vT,
                                                 gb);
  zbias_kernel<<<1152, 256, 0, stream>>>(z, w1th, w1tl, wcs, bh, biasb);
  attn_kernel<<<dim3(12, 16), 256, 0, stream>>>(qb, kb, vT, biasb, oX);
  outproj_kernel<<<dim3(12, 12), 256, 0, stream>>>(oX, gb, wt + 4 * (size_t)NN,
                                                   out);
}

// Round 3
// 554.919 us; speedup vs baseline: 1.1225x; 1.0628x over previous
//
#include <hip/hip_runtime.h>
#include <math.h>

constexpr int NT = 768;      // sequence length N
constexpr int DT = 768;      // model dim D
constexpr int HT = 16;       // heads
constexpr int HDT = 48;      // head dim
constexpr int ZDT = 128;     // pair-rep dim
constexpr int NN = NT * NT;  // 589824
constexpr float LN_EPS = 1e-5f;
constexpr float SCALE = 0.14433756729740643f;  // 48^-0.5
constexpr int KP = 72;       // LDS k-stride in bf16 elems (64 + 8 pad)

typedef __attribute__((ext_vector_type(8))) short bfrag;   // 8 bf16 (4 VGPR)
typedef __attribute__((ext_vector_type(4))) float ffrag;   // 4 fp32 acc

#define MFMA16(a, b, c) __builtin_amdgcn_mfma_f32_16x16x32_bf16(a, b, c, 0, 0, 0)

__device__ __forceinline__ short f2b(float f) {
  unsigned u = __builtin_bit_cast(unsigned, f);
  u += 0x7fffu + ((u >> 16) & 1u);   // RNE
  return (short)(u >> 16);
}
__device__ __forceinline__ float b2f(short s) {
  return __builtin_bit_cast(float, (unsigned)(unsigned short)s << 16);
}
// hi/lo bf16 split by truncation: hi16(f)+lo16(f) reconstructs f to ~2^-24 rel
__device__ __forceinline__ short hi16(float f) {
  return (short)(__builtin_bit_cast(unsigned, f) >> 16);
}
__device__ __forceinline__ short lo16(float f) {
  unsigned u = __builtin_bit_cast(unsigned, f);
  float r = f - __builtin_bit_cast(float, u & 0xffff0000u);  // exact in fp32
  return (short)(__builtin_bit_cast(unsigned, r) >> 16);
}
__device__ __forceinline__ float s4(float4 v) { return (v.x + v.y) + (v.z + v.w); }
__device__ __forceinline__ float q4(float4 v) {
  return (v.x * v.x + v.y * v.y) + (v.z * v.z + v.w * v.w);
}

// ---------------------------------------------------------------------------
// setup: fused  prep (blocks 0..719)  |  ln_s (720..1487)  |  zsetup (1488)
// ---------------------------------------------------------------------------
__global__ __launch_bounds__(256) void setup_kernel(
    const float* __restrict__ s, const float* __restrict__ nsw,
    const float* __restrict__ nsb, short* __restrict__ snb,
    const float* __restrict__ qw, const float* __restrict__ kw,
    const float* __restrict__ vw, const float* __restrict__ gw,
    const float* __restrict__ ow, short* __restrict__ wt,
    const float* __restrict__ znw, const float* __restrict__ znb,
    const float* __restrict__ zw, short* __restrict__ w1th,
    short* __restrict__ w1tl, float* __restrict__ wcs,
    float* __restrict__ bh) {
  const int bid = blockIdx.x;
  const int t = threadIdx.x;
  if (bid < 720) {
    // ---------------- prep branch (x=n-tile, y=k-tile, z=which flattened)
    __shared__ float Ts[64][65];
    const int which = bid / 144;
    const int rem = bid % 144;
    const int k0 = (rem / 12) * 64;
    const int n0 = (rem % 12) * 64;
    const float* src = which == 0 ? qw : which == 1 ? kw : which == 2 ? vw
                       : which == 3 ? gw : ow;
    short* dst = wt + (size_t)which * NN;
    const int r = t >> 4, c = (t & 15) * 4;
#pragma unroll
    for (int i = 0; i < 4; i++) {
      int rr = r + i * 16;
      float4 v = *(const float4*)&src[(size_t)(k0 + rr) * DT + n0 + c];
      Ts[rr][c + 0] = v.x; Ts[rr][c + 1] = v.y;
      Ts[rr][c + 2] = v.z; Ts[rr][c + 3] = v.w;
    }
    __syncthreads();
#pragma unroll
    for (int i = 0; i < 2; i++) {
      int cid = t + i * 256;          // 512 chunks of 8
      int nr = cid >> 3, kc = cid & 7;
      union { uint4 u; short s2[8]; } pk;
#pragma unroll
      for (int j = 0; j < 8; j++) pk.s2[j] = f2b(Ts[kc * 8 + j][nr]);
      *(uint4*)&dst[(size_t)(n0 + nr) * DT + k0 + kc * 8] = pk.u;
    }
  } else if (bid < 1488) {
    // ---------------- ln_s branch
    const int row = bid - 720;
    const float* x = s + row * DT;
    float v0 = x[t], v1 = x[t + 256], v2 = x[t + 512];
    float sum = v0 + v1 + v2;
    float sq = v0 * v0 + v1 * v1 + v2 * v2;
#pragma unroll
    for (int off = 32; off; off >>= 1) {
      sum += __shfl_xor(sum, off);
      sq += __shfl_xor(sq, off);
    }
    __shared__ float ls[4], lq[4], stats[2];
    const int wid = t >> 6;
    if ((t & 63) == 0) { ls[wid] = sum; lq[wid] = sq; }
    __syncthreads();
    if (t == 0) {
      float S = ls[0] + ls[1] + ls[2] + ls[3];
      float Q = lq[0] + lq[1] + lq[2] + lq[3];
      float mu = S * (1.f / DT);
      float var = Q * (1.f / DT) - mu * mu;
      stats[0] = mu;
      stats[1] = rsqrtf(var + LN_EPS);
    }
    __syncthreads();
    const float mu = stats[0], rs = stats[1];
    short* y = snb + row * DT;
    y[t] = f2b((v0 - mu) * rs * nsw[t] + nsb[t]);
    y[t + 256] = f2b((v1 - mu) * rs * nsw[t + 256] + nsb[t + 256]);
    y[t + 512] = f2b((v2 - mu) * rs * nsw[t + 512] + nsb[t + 512]);
  } else {
    // ---------------- zsetup branch
    __shared__ float sm[ZDT * HT];     // w1[c][h] = znw[c] * zw[c][h]
#pragma unroll
    for (int i = 0; i < 8; i++) {
      int idx = t * 8 + i;
      int c = idx >> 4;
      sm[idx] = znw[c] * zw[idx];
    }
    __syncthreads();
#pragma unroll
    for (int i = 0; i < 8; i++) {
      int idx = t * 8 + i;
      int c = idx >> 4, h = idx & 15;
      float v = sm[idx];
      short hi = f2b(v);
      w1th[h * ZDT + c] = hi;                 // W^T hi (bf16)
      w1tl[h * ZDT + c] = f2b(v - b2f(hi));   // W^T lo residual (bf16)
    }
    if (t < HT) {
      float s1 = 0.f, s2 = 0.f;
      for (int c = 0; c < ZDT; c++) s1 += sm[c * HT + t];
      wcs[t] = s1;                            // column sums of w1
      for (int c = 0; c < ZDT; c++) s2 += znb[c] * zw[c * HT + t];
      bh[t] = s2;                             // folded LN bias term
    }
  }
}

// ------------------------------- q/k/v/g projections via bf16 MFMA, 128x128
__global__ __launch_bounds__(256) void proj_kernel(
    const short* __restrict__ snb, const short* __restrict__ wt,
    const float* __restrict__ qbias, short* __restrict__ qb,
    short* __restrict__ kb, short* __restrict__ vT, short* __restrict__ gb) {
  __shared__ short As[128 * KP];
  __shared__ short Bs[128 * KP];
  const int t = threadIdx.x;
  const int which = blockIdx.z;
  const short* W = wt + (size_t)which * NN;
  const int N0 = blockIdx.x * 128;
  const int M0 = blockIdx.y * 128;
  const int w = t >> 6, l = t & 63;
  const int wm = (w >> 1) * 64, wn = (w & 1) * 64;
  const int lane16 = l & 15, quad = l >> 4;
  ffrag acc[4][4] = {};
  const int srow = t >> 3, skc = t & 7;
  for (int k0 = 0; k0 < DT; k0 += 64) {
    uint4 av[4], bv[4];
#pragma unroll
    for (int i = 0; i < 4; i++) {
      int row = srow + i * 32;
      av[i] = *(const uint4*)&snb[(size_t)(M0 + row) * DT + k0 + skc * 8];
      bv[i] = *(const uint4*)&W[(size_t)(N0 + row) * DT + k0 + skc * 8];
    }
    __syncthreads();
#pragma unroll
    for (int i = 0; i < 4; i++) {
      int row = srow + i * 32;
      *(uint4*)&As[row * KP + skc * 8] = av[i];
      *(uint4*)&Bs[row * KP + skc * 8] = bv[i];
    }
    __syncthreads();
#pragma unroll
    for (int ks = 0; ks < 2; ks++) {
      bfrag a[4], b[4];
#pragma unroll
      for (int i = 0; i < 4; i++)
        a[i] = *(const bfrag*)&As[(wm + i * 16 + lane16) * KP + ks * 32 + quad * 8];
#pragma unroll
      for (int j = 0; j < 4; j++)
        b[j] = *(const bfrag*)&Bs[(wn + j * 16 + lane16) * KP + ks * 32 + quad * 8];
#pragma unroll
      for (int i = 0; i < 4; i++)
#pragma unroll
        for (int j = 0; j < 4; j++) acc[i][j] = MFMA16(a[i], b[j], acc[i][j]);
    }
    __syncthreads();
  }
#pragma unroll
  for (int i = 0; i < 4; i++) {
#pragma unroll
    for (int j = 0; j < 4; j++) {
      int n = N0 + wn + j * 16 + lane16;
#pragma unroll
      for (int r = 0; r < 4; r++) {
        int m = M0 + wm + i * 16 + quad * 4 + r;
        float v = acc[i][j][r];
        if (which == 0) {
          qb[(size_t)m * DT + n] = f2b(v + qbias[n]);
        } else if (which == 1) {
          kb[(size_t)m * DT + n] = f2b(v);
        } else if (which == 2) {
          vT[(size_t)n * NT + m] = f2b(v);   // [h*48+d][seq] for AV B-operand
        } else {
          gb[(size_t)m * DT + n] = f2b(1.f / (1.f + __expf(-v)));
        }
      }
    }
  }
}

// ---------------------------------------------------------------------------
// zbias v4: bias[rid][h] = rs*(z[rid,:]@w1[:,h] - mu*colsum(w1)[h]) + bh[h]
// NO addressable locals (scratch-proof): 8 named float4 loads, component-wise
// stats, truncation hi/lo split straight into bfrag lanes, 3 independent MFMA
// chains. grid 2304 x 256 rows; ~105 VGPR, 0 LDS -> 4 waves/SIMD.
// ---------------------------------------------------------------------------
__global__ __launch_bounds__(256) void zbias_kernel(
    const float* __restrict__ z, const short* __restrict__ w1th,
    const short* __restrict__ w1tl, const float* __restrict__ wcs,
    const float* __restrict__ bh, short* __restrict__ biasb) {
  const int t = threadIdx.x;
  const int w = t >> 6, l = t & 63;
  const int lane16 = l & 15, quad = l >> 4;
  // loop-invariant B-frags: W^T[h=lane16][k], hi/lo, 4 k-steps (32 VGPR)
  const bfrag wh0 = *(const bfrag*)&w1th[lane16 * ZDT + 0 + quad * 8];
  const bfrag wh1 = *(const bfrag*)&w1th[lane16 * ZDT + 32 + quad * 8];
  const bfrag wh2 = *(const bfrag*)&w1th[lane16 * ZDT + 64 + quad * 8];
  const bfrag wh3 = *(const bfrag*)&w1th[lane16 * ZDT + 96 + quad * 8];
  const bfrag wl0 = *(const bfrag*)&w1tl[lane16 * ZDT + 0 + quad * 8];
  const bfrag wl1 = *(const bfrag*)&w1tl[lane16 * ZDT + 32 + quad * 8];
  const bfrag wl2 = *(const bfrag*)&w1tl[lane16 * ZDT + 64 + quad * 8];
  const bfrag wl3 = *(const bfrag*)&w1tl[lane16 * ZDT + 96 + quad * 8];
  const float wcs_h = wcs[lane16];
  const float bh_h = bh[lane16];
  const int row_base0 = blockIdx.x * 256 + w * 64;
#pragma unroll
  for (int it = 0; it < 4; it++) {
    const int rbase = row_base0 + it * 16;
    const float* zp = &z[(size_t)(rbase + lane16) * ZDT + quad * 8];
    const float4 a0 = *(const float4*)(zp + 0);
    const float4 b0 = *(const float4*)(zp + 4);
    const float4 a1 = *(const float4*)(zp + 32);
    const float4 b1 = *(const float4*)(zp + 36);
    const float4 a2 = *(const float4*)(zp + 64);
    const float4 b2 = *(const float4*)(zp + 68);
    const float4 a3 = *(const float4*)(zp + 96);
    const float4 b3 = *(const float4*)(zp + 100);
    // row stats (this lane holds 32 of 128 elems; combine the 4 quads)
    float sum = ((s4(a0) + s4(b0)) + (s4(a1) + s4(b1))) +
                ((s4(a2) + s4(b2)) + (s4(a3) + s4(b3)));
    float sq = ((q4(a0) + q4(b0)) + (q4(a1) + q4(b1))) +
               ((q4(a2) + q4(b2)) + (q4(a3) + q4(b3)));
    sum += __shfl_xor(sum, 16); sq += __shfl_xor(sq, 16);
    sum += __shfl_xor(sum, 32); sq += __shfl_xor(sq, 32);
    // truncation hi/lo split, built directly into frag lanes
    const bfrag xh0 = {hi16(a0.x), hi16(a0.y), hi16(a0.z), hi16(a0.w),
                       hi16(b0.x), hi16(b0.y), hi16(b0.z), hi16(b0.w)};
    const bfrag xl0 = {lo16(a0.x), lo16(a0.y), lo16(a0.z), lo16(a0.w),
                       lo16(b0.x), lo16(b0.y), lo16(b0.z), lo16(b0.w)};
    const bfrag xh1 = {hi16(a1.x), hi16(a1.y), hi16(a1.z), hi16(a1.w),
                       hi16(b1.x), hi16(b1.y), hi16(b1.z), hi16(b1.w)};
    const bfrag xl1 = {lo16(a1.x), lo16(a1.y), lo16(a1.z), lo16(a1.w),
                       lo16(b1.x), lo16(b1.y), lo16(b1.z), lo16(b1.w)};
    const bfrag xh2 = {hi16(a2.x), hi16(a2.y), hi16(a2.z), hi16(a2.w),
                       hi16(b2.x), hi16(b2.y), hi16(b2.z), hi16(b2.w)};
    const bfrag xl2 = {lo16(a2.x), lo16(a2.y), lo16(a2.z), lo16(a2.w),
                       lo16(b2.x), lo16(b2.y), lo16(b2.z), lo16(b2.w)};
    const bfrag xh3 = {hi16(a3.x), hi16(a3.y), hi16(a3.z), hi16(a3.w),
                       hi16(b3.x), hi16(b3.y), hi16(b3.z), hi16(b3.w)};
    const bfrag xl3 = {lo16(a3.x), lo16(a3.y), lo16(a3.z), lo16(a3.w),
                       lo16(b3.x), lo16(b3.y), lo16(b3.z), lo16(b3.w)};
    // 3 independent accumulation chains (4 MFMAs each)
    ffrag accA = {0.f, 0.f, 0.f, 0.f};   // xh * Wh
    ffrag accB = {0.f, 0.f, 0.f, 0.f};   // xl * Wh
    ffrag accC = {0.f, 0.f, 0.f, 0.f};   // xh * Wl
    accA = MFMA16(xh0, wh0, accA);
    accB = MFMA16(xl0, wh0, accB);
    accC = MFMA16(xh0, wl0, accC);
    accA = MFMA16(xh1, wh1, accA);
    accB = MFMA16(xl1, wh1, accB);
    accC = MFMA16(xh1, wl1, accC);
    accA = MFMA16(xh2, wh2, accA);
    accB = MFMA16(xl2, wh2, accB);
    accC = MFMA16(xh2, wl2, accC);
    accA = MFMA16(xh3, wh3, accA);
    accB = MFMA16(xl3, wh3, accB);
    accC = MFMA16(xh3, wl3, accC);
    // epilogue: C[row=quad*4+r][h=lane16]; row stats fetched by shuffle
    union { uint2 u; short s2[4]; } pk;
#pragma unroll
    for (int r = 0; r < 4; r++) {
      float rsum = __shfl(sum, quad * 4 + r);
      float rsq = __shfl(sq, quad * 4 + r);
      float mu = rsum * (1.f / 128.f);
      float rs = rsqrtf(rsq * (1.f / 128.f) - mu * mu + LN_EPS);
      float av = (accA[r] + accB[r]) + accC[r];
      pk.s2[r] = f2b(rs * (av - mu * wcs_h) + bh_h);
    }
    *(uint2*)&biasb[(size_t)lane16 * NN + rbase + quad * 4] = pk.u;
  }
}

// ------- fused attention: S=QK^T*scale+bias, online softmax, O=PV
// grid (12 q-tiles of 64, 16 heads); 4 waves, wave w owns q-rows w*16..+16
__global__ __launch_bounds__(256) void attn_kernel(
    const short* __restrict__ qb, const short* __restrict__ kb,
    const short* __restrict__ vT, const short* __restrict__ biasb,
    float* __restrict__ oX) {
  __shared__ short Ks[128 * 48];       // [kpos][d]
  __shared__ short Vs[48 * 136];       // [d][kpos+8 pad]
  __shared__ short Ps[4][16 * 136];    // per-wave private P slice
  const int t = threadIdx.x;
  const int h = blockIdx.y;
  const int q0 = blockIdx.x * 64;
  const int w = t >> 6, l = t & 63;
  const int lane16 = l & 15, quad = l >> 4;
  const int qrow = q0 + w * 16 + lane16;
  bfrag a_q0 = *(const bfrag*)&qb[(size_t)qrow * DT + h * HDT + quad * 8];
  bfrag a_q1 = {0, 0, 0, 0, 0, 0, 0, 0};   // k 48..63 zero-padded
  if (quad < 2)
    a_q1 = *(const bfrag*)&qb[(size_t)qrow * DT + h * HDT + 32 + quad * 8];
  const int koff1 = (quad < 2) ? (32 + quad * 8) : 0;
  ffrag acc_o[3] = {};
  float m_run[4] = {-1e30f, -1e30f, -1e30f, -1e30f};
  float l_run[4] = {};
  const size_t bias_base =
      (size_t)h * NN + (size_t)(q0 + w * 16 + quad * 4) * NT + lane16;
  for (int kt = 0; kt < 6; kt++) {
    const int k0 = kt * 128;
    uint4 kv[3], vv[3];
#pragma unroll
    for (int i = 0; i < 3; i++) {
      int cid = t + i * 256;
      int kr = cid / 6, kc = cid % 6;
      kv[i] = *(const uint4*)&kb[(size_t)(k0 + kr) * DT + h * HDT + kc * 8];
      int vr = cid >> 4, vc = cid & 15;
      vv[i] = *(const uint4*)&vT[((size_t)h * HDT + vr) * NT + k0 + vc * 8];
    }
    short bias_s[8][4];
#pragma unroll
    for (int j = 0; j < 8; j++)
#pragma unroll
      for (int r = 0; r < 4; r++)
        bias_s[j][r] = biasb[bias_base + (size_t)r * NT + k0 + j * 16];
    __syncthreads();
#pragma unroll
    for (int i = 0; i < 3; i++) {
      int cid = t + i * 256;
      int kr = cid / 6, kc = cid % 6;
      *(uint4*)&Ks[kr * 48 + kc * 8] = kv[i];
      int vr = cid >> 4, vc = cid & 15;
      *(uint4*)&Vs[vr * 136 + vc * 8] = vv[i];
    }
    __syncthreads();
    // S = Q K^T   (8 n-tiles x 2 k-steps)
    ffrag sc[8];
#pragma unroll
    for (int j = 0; j < 8; j++) {
      ffrag zf = {0.f, 0.f, 0.f, 0.f};
      bfrag b0 = *(const bfrag*)&Ks[(j * 16 + lane16) * 48 + quad * 8];
      bfrag b1 = *(const bfrag*)&Ks[(j * 16 + lane16) * 48 + koff1];
      zf = MFMA16(a_q0, b0, zf);
      sc[j] = MFMA16(a_q1, b1, zf);
    }
    // logits + online softmax (C layout: col=lane16, row=quad*4+r)
    float li[8][4];
#pragma unroll
    for (int j = 0; j < 8; j++)
#pragma unroll
      for (int r = 0; r < 4; r++)
        li[j][r] = sc[j][r] * SCALE + b2f(bias_s[j][r]);
    float alpha[4];
#pragma unroll
    for (int r = 0; r < 4; r++) {
      float m = li[0][r];
#pragma unroll
      for (int j = 1; j < 8; j++) m = fmaxf(m, li[j][r]);
#pragma unroll
      for (int k = 1; k <= 8; k <<= 1) m = fmaxf(m, __shfl_xor(m, k));
      float mn = fmaxf(m_run[r], m);
      alpha[r] = __expf(m_run[r] - mn);
      m_run[r] = mn;
    }
#pragma unroll
    for (int j = 0; j < 8; j++)
#pragma unroll
      for (int r = 0; r < 4; r++) li[j][r] = __expf(li[j][r] - m_run[r]);
#pragma unroll
    for (int r = 0; r < 4; r++) {
      float ssum = li[0][r];
#pragma unroll
      for (int j = 1; j < 8; j++) ssum += li[j][r];
#pragma unroll
      for (int k = 1; k <= 8; k <<= 1) ssum += __shfl_xor(ssum, k);
      l_run[r] = l_run[r] * alpha[r] + ssum;
    }
#pragma unroll
    for (int dt = 0; dt < 3; dt++)
#pragma unroll
      for (int r = 0; r < 4; r++) acc_o[dt][r] *= alpha[r];
#pragma unroll
    for (int j = 0; j < 8; j++)
#pragma unroll
      for (int r = 0; r < 4; r++)
        Ps[w][(quad * 4 + r) * 136 + j * 16 + lane16] = f2b(li[j][r]);
    // O += P V   (3 d-tiles x 4 k-steps)
#pragma unroll
    for (int ks = 0; ks < 4; ks++) {
      bfrag ap = *(const bfrag*)&Ps[w][lane16 * 136 + ks * 32 + quad * 8];
#pragma unroll
      for (int dt = 0; dt < 3; dt++) {
        bfrag bv = *(const bfrag*)&Vs[(dt * 16 + lane16) * 136 + ks * 32 + quad * 8];
        acc_o[dt] = MFMA16(ap, bv, acc_o[dt]);
      }
    }
  }
  float inv[4];
#pragma unroll
  for (int r = 0; r < 4; r++) inv[r] = 1.f / l_run[r];
#pragma unroll
  for (int dt = 0; dt < 3; dt++)
#pragma unroll
    for (int r = 0; r < 4; r++)
      oX[(size_t)(q0 + w * 16 + quad * 4 + r) * DT + h * HDT + dt * 16 + lane16] =
          acc_o[dt][r] * inv[r];
}

// ---------------------------- out = (o .* g) @ o_w via bf16 MFMA, 64x64 tiles
__global__ __launch_bounds__(256) void outproj_kernel(
    const float* __restrict__ oX, const short* __restrict__ gb,
    const short* __restrict__ owt, float* __restrict__ out) {
  __shared__ short As[64 * KP];
  __shared__ short Bs[64 * KP];
  const int t = threadIdx.x;
  const int N0 = blockIdx.x * 64;
  const int M0 = blockIdx.y * 64;
  const int w = t >> 6, l = t & 63;
  const int wm = (w >> 1) * 32, wn = (w & 1) * 32;
  const int lane16 = l & 15, quad = l >> 4;
  ffrag acc[2][2] = {};
  const int srow = t >> 2;          // 0..63
  const int sc = (t & 3) * 16;      // elem offset 0/16/32/48
  for (int k0 = 0; k0 < DT; k0 += 64) {
    uint4 apk[2], bvv[2];
    const float* op = &oX[(size_t)(M0 + srow) * DT + k0 + sc];
    const short* gp = &gb[(size_t)(M0 + srow) * DT + k0 + sc];
    const short* bp = &owt[(size_t)(N0 + srow) * DT + k0 + sc];
#pragma unroll
    for (int i = 0; i < 2; i++) {
      float4 o0 = *(const float4*)&op[i * 8 + 0];
      float4 o1 = *(const float4*)&op[i * 8 + 4];
      union { uint4 u; short s2[8]; } gv;
      gv.u = *(const uint4*)&gp[i * 8];
      union { uint4 u; short s2[8]; } pk;
      float go[8] = {o0.x, o0.y, o0.z, o0.w, o1.x, o1.y, o1.z, o1.w};
#pragma unroll
      for (int jj = 0; jj < 8; jj++) pk.s2[jj] = f2b(go[jj] * b2f(gv.s2[jj]));
      apk[i] = pk.u;
      bvv[i] = *(const uint4*)&bp[i * 8];
    }
    __syncthreads();
    *(uint4*)&As[srow * KP + sc] = apk[0];
    *(uint4*)&As[srow * KP + sc + 8] = apk[1];
    *(uint4*)&Bs[srow * KP + sc] = bvv[0];
    *(uint4*)&Bs[srow * KP + sc + 8] = bvv[1];
    __syncthreads();
#pragma unroll
    for (int ks = 0; ks < 2; ks++) {
      bfrag a[2], b[2];
#pragma unroll
      for (int i = 0; i < 2; i++)
        a[i] = *(const bfrag*)&As[(wm + i * 16 + lane16) * KP + ks * 32 + quad * 8];
#pragma unroll
      for (int j = 0; j < 2; j++)
        b[j] = *(const bfrag*)&Bs[(wn + j * 16 + lane16) * KP + ks * 32 + quad * 8];
#pragma unroll
      for (int i = 0; i < 2; i++)
#pragma unroll
        for (int j = 0; j < 2; j++) acc[i][j] = MFMA16(a[i], b[j], acc[i][j]);
    }
  }
#pragma unroll
  for (int i = 0; i < 2; i++)
#pragma unroll
    for (int j = 0; j < 2; j++) {
      int n = N0 + wn + j * 16 + lane16;
#pragma unroll
      for (int r = 0; r < 4; r++) {
        int m = M0 + wm + i * 16 + quad * 4 + r;
        out[(size_t)m * DT + n] = acc[i][j][r];
      }
    }
}

extern "C" void kernel_launch(void* const* d_in, const int* in_sizes, int n_in,
                              void* d_out, int out_size, void* d_ws,
                              size_t ws_size, hipStream_t stream) {
  const float* s = (const float*)d_in[0];
  const float* z = (const float*)d_in[1];
  const float* nsw = (const float*)d_in[2];
  const float* nsb = (const float*)d_in[3];
  const float* qw = (const float*)d_in[4];
  const float* qbias = (const float*)d_in[5];
  const float* kw = (const float*)d_in[6];
  const float* vw = (const float*)d_in[7];
  const float* gw = (const float*)d_in[8];
  const float* znw = (const float*)d_in[9];
  const float* znb = (const float*)d_in[10];
  const float* zww = (const float*)d_in[11];
  const float* ow = (const float*)d_in[12];
  float* out = (float*)d_out;
  char* W = (char*)d_ws;

  short* biasb = (short*)W;                        // 18,874,368 B
  short* snb = (short*)(W + 18874368);             // 1,179,648 B
  short* qb = (short*)(W + 20054016);
  short* kb = (short*)(W + 21233664);
  short* gb = (short*)(W + 22413312);
  short* vT = (short*)(W + 23592960);
  short* wt = (short*)(W + 24772608);              // 5 x 1,179,648 B
  float* oX = (float*)(W + 30670848);              // 2,359,296 B
  short* w1th = (short*)(W + 33030144);            // 4096 B
  short* w1tl = (short*)(W + 33034240);            // 4096 B
  float* wcs = (float*)(W + 33038336);             // 64 B
  float* bh = (float*)(W + 33038400);              // 64 B

  // setup -> proj -> zbias(MFMA, scratch-free) -> attn -> outproj
  setup_kernel<<<1489, 256, 0, stream>>>(s, nsw, nsb, snb, qw, kw, vw, gw, ow,
                                         wt, znw, znb, zww, w1th, w1tl, wcs,
                                         bh);
  proj_kernel<<<dim3(6, 6, 4), 256, 0, stream>>>(snb, wt, qbias, qb, kb, vT,
                                                 gb);
  zbias_kernel<<<2304, 256, 0, stream>>>(z, w1th, w1tl, wcs, bh, biasb);
  attn_kernel<<<dim3(12, 16), 256, 0, stream>>>(qb, kb, vT, biasb, oX);
  outproj_kernel<<<dim3(12, 12), 256, 0, stream>>>(oX, gb, wt + 4 * (size_t)NN,
                                                   out);
}

// Round 5
// 543.709 us; speedup vs baseline: 1.1456x; 1.0206x over previous
//
#include <hip/hip_runtime.h>
#include <math.h>

constexpr int NT = 768;      // sequence length N
constexpr int DT = 768;      // model dim D
constexpr int HT = 16;       // heads
constexpr int HDT = 48;      // head dim
constexpr int ZDT = 128;     // pair-rep dim
constexpr int NN = NT * NT;  // 589824
constexpr float LN_EPS = 1e-5f;
constexpr float SCALE = 0.14433756729740643f;  // 48^-0.5
constexpr int KP = 72;       // LDS k-stride in bf16 elems (64 + 8 pad)

typedef __attribute__((ext_vector_type(8))) short bfrag;   // 8 bf16 (4 VGPR)
typedef __attribute__((ext_vector_type(4))) float ffrag;   // 4 fp32 acc
typedef __attribute__((ext_vector_type(4))) float f4;      // clang ext-vector
                                                           // (nt-load legal)

#define MFMA16(a, b, c) __builtin_amdgcn_mfma_f32_16x16x32_bf16(a, b, c, 0, 0, 0)

__device__ __forceinline__ short f2b(float f) {
  unsigned u = __builtin_bit_cast(unsigned, f);
  u += 0x7fffu + ((u >> 16) & 1u);   // RNE
  return (short)(u >> 16);
}
__device__ __forceinline__ float b2f(short s) {
  return __builtin_bit_cast(float, (unsigned)(unsigned short)s << 16);
}
// hi/lo bf16 split by truncation: hi16(f)+lo16(f) reconstructs f to ~2^-24 rel
__device__ __forceinline__ short hi16(float f) {
  return (short)(__builtin_bit_cast(unsigned, f) >> 16);
}
__device__ __forceinline__ short lo16(float f) {
  unsigned u = __builtin_bit_cast(unsigned, f);
  float r = f - __builtin_bit_cast(float, u & 0xffff0000u);  // exact in fp32
  return (short)(__builtin_bit_cast(unsigned, r) >> 16);
}
__device__ __forceinline__ float s4v(f4 v) { return (v.x + v.y) + (v.z + v.w); }
__device__ __forceinline__ float q4v(f4 v) {
  return (v.x * v.x + v.y * v.y) + (v.z * v.z + v.w * v.w);
}

// ---------------------------------------------------------------------------
// setup: fused  prep (blocks 0..719)  |  ln_s (720..1487)  |  zsetup (1488)
// ---------------------------------------------------------------------------
__global__ __launch_bounds__(256) void setup_kernel(
    const float* __restrict__ s, const float* __restrict__ nsw,
    const float* __restrict__ nsb, short* __restrict__ snb,
    const float* __restrict__ qw, const float* __restrict__ kw,
    const float* __restrict__ vw, const float* __restrict__ gw,
    const float* __restrict__ ow, short* __restrict__ wt,
    const float* __restrict__ znw, const float* __restrict__ znb,
    const float* __restrict__ zw, short* __restrict__ w1th,
    short* __restrict__ w1tl, float* __restrict__ wcs,
    float* __restrict__ bh) {
  const int bid = blockIdx.x;
  const int t = threadIdx.x;
  if (bid < 720) {
    // ---------------- prep branch (x=n-tile, y=k-tile, z=which flattened)
    __shared__ float Ts[64][65];
    const int which = bid / 144;
    const int rem = bid % 144;
    const int k0 = (rem / 12) * 64;
    const int n0 = (rem % 12) * 64;
    const float* src = which == 0 ? qw : which == 1 ? kw : which == 2 ? vw
                       : which == 3 ? gw : ow;
    short* dst = wt + (size_t)which * NN;
    const int r = t >> 4, c = (t & 15) * 4;
#pragma unroll
    for (int i = 0; i < 4; i++) {
      int rr = r + i * 16;
      float4 v = *(const float4*)&src[(size_t)(k0 + rr) * DT + n0 + c];
      Ts[rr][c + 0] = v.x; Ts[rr][c + 1] = v.y;
      Ts[rr][c + 2] = v.z; Ts[rr][c + 3] = v.w;
    }
    __syncthreads();
#pragma unroll
    for (int i = 0; i < 2; i++) {
      int cid = t + i * 256;          // 512 chunks of 8
      int nr = cid >> 3, kc = cid & 7;
      union { uint4 u; short s2[8]; } pk;
#pragma unroll
      for (int j = 0; j < 8; j++) pk.s2[j] = f2b(Ts[kc * 8 + j][nr]);
      *(uint4*)&dst[(size_t)(n0 + nr) * DT + k0 + kc * 8] = pk.u;
    }
  } else if (bid < 1488) {
    // ---------------- ln_s branch
    const int row = bid - 720;
    const float* x = s + row * DT;
    float v0 = x[t], v1 = x[t + 256], v2 = x[t + 512];
    float sum = v0 + v1 + v2;
    float sq = v0 * v0 + v1 * v1 + v2 * v2;
#pragma unroll
    for (int off = 32; off; off >>= 1) {
      sum += __shfl_xor(sum, off);
      sq += __shfl_xor(sq, off);
    }
    __shared__ float ls[4], lq[4], stats[2];
    const int wid = t >> 6;
    if ((t & 63) == 0) { ls[wid] = sum; lq[wid] = sq; }
    __syncthreads();
    if (t == 0) {
      float S = ls[0] + ls[1] + ls[2] + ls[3];
      float Q = lq[0] + lq[1] + lq[2] + lq[3];
      float mu = S * (1.f / DT);
      float var = Q * (1.f / DT) - mu * mu;
      stats[0] = mu;
      stats[1] = rsqrtf(var + LN_EPS);
    }
    __syncthreads();
    const float mu = stats[0], rs = stats[1];
    short* y = snb + row * DT;
    y[t] = f2b((v0 - mu) * rs * nsw[t] + nsb[t]);
    y[t + 256] = f2b((v1 - mu) * rs * nsw[t + 256] + nsb[t + 256]);
    y[t + 512] = f2b((v2 - mu) * rs * nsw[t + 512] + nsb[t + 512]);
  } else {
    // ---------------- zsetup branch
    __shared__ float sm[ZDT * HT];     // w1[c][h] = znw[c] * zw[c][h]
#pragma unroll
    for (int i = 0; i < 8; i++) {
      int idx = t * 8 + i;
      int c = idx >> 4;
      sm[idx] = znw[c] * zw[idx];
    }
    __syncthreads();
#pragma unroll
    for (int i = 0; i < 8; i++) {
      int idx = t * 8 + i;
      int c = idx >> 4, h = idx & 15;
      float v = sm[idx];
      short hi = f2b(v);
      w1th[h * ZDT + c] = hi;                 // W^T hi (bf16)
      w1tl[h * ZDT + c] = f2b(v - b2f(hi));   // W^T lo residual (bf16)
    }
    if (t < HT) {
      float s1 = 0.f, s2 = 0.f;
      for (int c = 0; c < ZDT; c++) s1 += sm[c * HT + t];
      wcs[t] = s1;                            // column sums of w1
      for (int c = 0; c < ZDT; c++) s2 += znb[c] * zw[c * HT + t];
      bh[t] = s2;                             // folded LN bias term
    }
  }
}

// ------------------------------- q/k/v/g projections via bf16 MFMA, 128x128
__global__ __launch_bounds__(256) void proj_kernel(
    const short* __restrict__ snb, const short* __restrict__ wt,
    const float* __restrict__ qbias, short* __restrict__ qb,
    short* __restrict__ kb, short* __restrict__ vT, short* __restrict__ gb) {
  __shared__ short As[128 * KP];
  __shared__ short Bs[128 * KP];
  const int t = threadIdx.x;
  const int which = blockIdx.z;
  const short* W = wt + (size_t)which * NN;
  const int N0 = blockIdx.x * 128;
  const int M0 = blockIdx.y * 128;
  const int w = t >> 6, l = t & 63;
  const int wm = (w >> 1) * 64, wn = (w & 1) * 64;
  const int lane16 = l & 15, quad = l >> 4;
  ffrag acc[4][4] = {};
  const int srow = t >> 3, skc = t & 7;
  for (int k0 = 0; k0 < DT; k0 += 64) {
    uint4 av[4], bv[4];
#pragma unroll
    for (int i = 0; i < 4; i++) {
      int row = srow + i * 32;
      av[i] = *(const uint4*)&snb[(size_t)(M0 + row) * DT + k0 + skc * 8];
      bv[i] = *(const uint4*)&W[(size_t)(N0 + row) * DT + k0 + skc * 8];
    }
    __syncthreads();
#pragma unroll
    for (int i = 0; i < 4; i++) {
      int row = srow + i * 32;
      *(uint4*)&As[row * KP + skc * 8] = av[i];
      *(uint4*)&Bs[row * KP + skc * 8] = bv[i];
    }
    __syncthreads();
#pragma unroll
    for (int ks = 0; ks < 2; ks++) {
      bfrag a[4], b[4];
#pragma unroll
      for (int i = 0; i < 4; i++)
        a[i] = *(const bfrag*)&As[(wm + i * 16 + lane16) * KP + ks * 32 + quad * 8];
#pragma unroll
      for (int j = 0; j < 4; j++)
        b[j] = *(const bfrag*)&Bs[(wn + j * 16 + lane16) * KP + ks * 32 + quad * 8];
#pragma unroll
      for (int i = 0; i < 4; i++)
#pragma unroll
        for (int j = 0; j < 4; j++) acc[i][j] = MFMA16(a[i], b[j], acc[i][j]);
    }
    __syncthreads();
  }
#pragma unroll
  for (int i = 0; i < 4; i++) {
#pragma unroll
    for (int j = 0; j < 4; j++) {
      int n = N0 + wn + j * 16 + lane16;
#pragma unroll
      for (int r = 0; r < 4; r++) {
        int m = M0 + wm + i * 16 + quad * 4 + r;
        float v = acc[i][j][r];
        if (which == 0) {
          qb[(size_t)m * DT + n] = f2b(v + qbias[n]);
        } else if (which == 1) {
          kb[(size_t)m * DT + n] = f2b(v);
        } else if (which == 2) {
          vT[(size_t)n * NT + m] = f2b(v);   // [h*48+d][seq] for AV B-operand
        } else {
          gb[(size_t)m * DT + n] = f2b(1.f / (1.f + __expf(-v)));
        }
      }
    }
  }
}

// ---------------------------------------------------------------------------
// zbias v5 = v4 + NONTEMPORAL z loads (single-variable change).
// Theory: the 2x1.2GB harness fills leave L3 full of dirty lines; zbias's
// 302 MB read-once z stream forces their eviction/writeback inside our timed
// window. nt loads skip cache allocation -> no forced flush.
// (r4 fix: nt-load requires clang ext_vector ptr, not HIP_vector_type.)
// ---------------------------------------------------------------------------
__global__ __launch_bounds__(256) void zbias_kernel(
    const float* __restrict__ z, const short* __restrict__ w1th,
    const short* __restrict__ w1tl, const float* __restrict__ wcs,
    const float* __restrict__ bh, short* __restrict__ biasb) {
  const int t = threadIdx.x;
  const int w = t >> 6, l = t & 63;
  const int lane16 = l & 15, quad = l >> 4;
  // loop-invariant B-frags: W^T[h=lane16][k], hi/lo, 4 k-steps (32 VGPR)
  const bfrag wh0 = *(const bfrag*)&w1th[lane16 * ZDT + 0 + quad * 8];
  const bfrag wh1 = *(const bfrag*)&w1th[lane16 * ZDT + 32 + quad * 8];
  const bfrag wh2 = *(const bfrag*)&w1th[lane16 * ZDT + 64 + quad * 8];
  const bfrag wh3 = *(const bfrag*)&w1th[lane16 * ZDT + 96 + quad * 8];
  const bfrag wl0 = *(const bfrag*)&w1tl[lane16 * ZDT + 0 + quad * 8];
  const bfrag wl1 = *(const bfrag*)&w1tl[lane16 * ZDT + 32 + quad * 8];
  const bfrag wl2 = *(const bfrag*)&w1tl[lane16 * ZDT + 64 + quad * 8];
  const bfrag wl3 = *(const bfrag*)&w1tl[lane16 * ZDT + 96 + quad * 8];
  const float wcs_h = wcs[lane16];
  const float bh_h = bh[lane16];
  const int row_base0 = blockIdx.x * 256 + w * 64;
#pragma unroll
  for (int it = 0; it < 4; it++) {
    const int rbase = row_base0 + it * 16;
    const float* zp = &z[(size_t)(rbase + lane16) * ZDT + quad * 8];
    const f4 a0 = __builtin_nontemporal_load((const f4*)(zp + 0));
    const f4 b0 = __builtin_nontemporal_load((const f4*)(zp + 4));
    const f4 a1 = __builtin_nontemporal_load((const f4*)(zp + 32));
    const f4 b1 = __builtin_nontemporal_load((const f4*)(zp + 36));
    const f4 a2 = __builtin_nontemporal_load((const f4*)(zp + 64));
    const f4 b2 = __builtin_nontemporal_load((const f4*)(zp + 68));
    const f4 a3 = __builtin_nontemporal_load((const f4*)(zp + 96));
    const f4 b3 = __builtin_nontemporal_load((const f4*)(zp + 100));
    // row stats (this lane holds 32 of 128 elems; combine the 4 quads)
    float sum = ((s4v(a0) + s4v(b0)) + (s4v(a1) + s4v(b1))) +
                ((s4v(a2) + s4v(b2)) + (s4v(a3) + s4v(b3)));
    float sq = ((q4v(a0) + q4v(b0)) + (q4v(a1) + q4v(b1))) +
               ((q4v(a2) + q4v(b2)) + (q4v(a3) + q4v(b3)));
    sum += __shfl_xor(sum, 16); sq += __shfl_xor(sq, 16);
    sum += __shfl_xor(sum, 32); sq += __shfl_xor(sq, 32);
    // truncation hi/lo split, built directly into frag lanes
    const bfrag xh0 = {hi16(a0.x), hi16(a0.y), hi16(a0.z), hi16(a0.w),
                       hi16(b0.x), hi16(b0.y), hi16(b0.z), hi16(b0.w)};
    const bfrag xl0 = {lo16(a0.x), lo16(a0.y), lo16(a0.z), lo16(a0.w),
                       lo16(b0.x), lo16(b0.y), lo16(b0.z), lo16(b0.w)};
    const bfrag xh1 = {hi16(a1.x), hi16(a1.y), hi16(a1.z), hi16(a1.w),
                       hi16(b1.x), hi16(b1.y), hi16(b1.z), hi16(b1.w)};
    const bfrag xl1 = {lo16(a1.x), lo16(a1.y), lo16(a1.z), lo16(a1.w),
                       lo16(b1.x), lo16(b1.y), lo16(b1.z), lo16(b1.w)};
    const bfrag xh2 = {hi16(a2.x), hi16(a2.y), hi16(a2.z), hi16(a2.w),
                       hi16(b2.x), hi16(b2.y), hi16(b2.z), hi16(b2.w)};
    const bfrag xl2 = {lo16(a2.x), lo16(a2.y), lo16(a2.z), lo16(a2.w),
                       lo16(b2.x), lo16(b2.y), lo16(b2.z), lo16(b2.w)};
    const bfrag xh3 = {hi16(a3.x), hi16(a3.y), hi16(a3.z), hi16(a3.w),
                       hi16(b3.x), hi16(b3.y), hi16(b3.z), hi16(b3.w)};
    const bfrag xl3 = {lo16(a3.x), lo16(a3.y), lo16(a3.z), lo16(a3.w),
                       lo16(b3.x), lo16(b3.y), lo16(b3.z), lo16(b3.w)};
    // 3 independent accumulation chains (4 MFMAs each)
    ffrag accA = {0.f, 0.f, 0.f, 0.f};   // xh * Wh
    ffrag accB = {0.f, 0.f, 0.f, 0.f};   // xl * Wh
    ffrag accC = {0.f, 0.f, 0.f, 0.f};   // xh * Wl
    accA = MFMA16(xh0, wh0, accA);
    accB = MFMA16(xl0, wh0, accB);
    accC = MFMA16(xh0, wl0, accC);
    accA = MFMA16(xh1, wh1, accA);
    accB = MFMA16(xl1, wh1, accB);
    accC = MFMA16(xh1, wl1, accC);
    accA = MFMA16(xh2, wh2, accA);
    accB = MFMA16(xl2, wh2, accB);
    accC = MFMA16(xh2, wl2, accC);
    accA = MFMA16(xh3, wh3, accA);
    accB = MFMA16(xl3, wh3, accB);
    accC = MFMA16(xh3, wl3, accC);
    // epilogue: C[row=quad*4+r][h=lane16]; row stats fetched by shuffle
    union { uint2 u; short s2[4]; } pk;
#pragma unroll
    for (int r = 0; r < 4; r++) {
      float rsum = __shfl(sum, quad * 4 + r);
      float rsq = __shfl(sq, quad * 4 + r);
      float mu = rsum * (1.f / 128.f);
      float rs = rsqrtf(rsq * (1.f / 128.f) - mu * mu + LN_EPS);
      float av = (accA[r] + accB[r]) + accC[r];
      pk.s2[r] = f2b(rs * (av - mu * wcs_h) + bh_h);
    }
    *(uint2*)&biasb[(size_t)lane16 * NN + rbase + quad * 4] = pk.u;
  }
}

// ------- fused attention: S=QK^T*scale+bias, online softmax, O=PV
// grid (12 q-tiles of 64, 16 heads); 4 waves, wave w owns q-rows w*16..+16
__global__ __launch_bounds__(256) void attn_kernel(
    const short* __restrict__ qb, const short* __restrict__ kb,
    const short* __restrict__ vT, const short* __restrict__ biasb,
    float* __restrict__ oX) {
  __shared__ short Ks[128 * 48];       // [kpos][d]
  __shared__ short Vs[48 * 136];       // [d][kpos+8 pad]
  __shared__ short Ps[4][16 * 136];    // per-wave private P slice
  const int t = threadIdx.x;
  const int h = blockIdx.y;
  const int q0 = blockIdx.x * 64;
  const int w = t >> 6, l = t & 63;
  const int lane16 = l & 15, quad = l >> 4;
  const int qrow = q0 + w * 16 + lane16;
  bfrag a_q0 = *(const bfrag*)&qb[(size_t)qrow * DT + h * HDT + quad * 8];
  bfrag a_q1 = {0, 0, 0, 0, 0, 0, 0, 0};   // k 48..63 zero-padded
  if (quad < 2)
    a_q1 = *(const bfrag*)&qb[(size_t)qrow * DT + h * HDT + 32 + quad * 8];
  const int koff1 = (quad < 2) ? (32 + quad * 8) : 0;
  ffrag acc_o[3] = {};
  float m_run[4] = {-1e30f, -1e30f, -1e30f, -1e30f};
  float l_run[4] = {};
  const size_t bias_base =
      (size_t)h * NN + (size_t)(q0 + w * 16 + quad * 4) * NT + lane16;
  for (int kt = 0; kt < 6; kt++) {
    const int k0 = kt * 128;
    uint4 kv[3], vv[3];
#pragma unroll
    for (int i = 0; i < 3; i++) {
      int cid = t + i * 256;
      int kr = cid / 6, kc = cid % 6;
      kv[i] = *(const uint4*)&kb[(size_t)(k0 + kr) * DT + h * HDT + kc * 8];
      int vr = cid >> 4, vc = cid & 15;
      vv[i] = *(const uint4*)&vT[((size_t)h * HDT + vr) * NT + k0 + vc * 8];
    }
    short bias_s[8][4];
#pragma unroll
    for (int j = 0; j < 8; j++)
#pragma unroll
      for (int r = 0; r < 4; r++)
        bias_s[j][r] = biasb[bias_base + (size_t)r * NT + k0 + j * 16];
    __syncthreads();
#pragma unroll
    for (int i = 0; i < 3; i++) {
      int cid = t + i * 256;
      int kr = cid / 6, kc = cid % 6;
      *(uint4*)&Ks[kr * 48 + kc * 8] = kv[i];
      int vr = cid >> 4, vc = cid & 15;
      *(uint4*)&Vs[vr * 136 + vc * 8] = vv[i];
    }
    __syncthreads();
    // S = Q K^T   (8 n-tiles x 2 k-steps)
    ffrag sc[8];
#pragma unroll
    for (int j = 0; j < 8; j++) {
      ffrag zf = {0.f, 0.f, 0.f, 0.f};
      bfrag b0 = *(const bfrag*)&Ks[(j * 16 + lane16) * 48 + quad * 8];
      bfrag b1 = *(const bfrag*)&Ks[(j * 16 + lane16) * 48 + koff1];
      zf = MFMA16(a_q0, b0, zf);
      sc[j] = MFMA16(a_q1, b1, zf);
    }
    // logits + online softmax (C layout: col=lane16, row=quad*4+r)
    float li[8][4];
#pragma unroll
    for (int j = 0; j < 8; j++)
#pragma unroll
      for (int r = 0; r < 4; r++)
        li[j][r] = sc[j][r] * SCALE + b2f(bias_s[j][r]);
    float alpha[4];
#pragma unroll
    for (int r = 0; r < 4; r++) {
      float m = li[0][r];
#pragma unroll
      for (int j = 1; j < 8; j++) m = fmaxf(m, li[j][r]);
#pragma unroll
      for (int k = 1; k <= 8; k <<= 1) m = fmaxf(m, __shfl_xor(m, k));
      float mn = fmaxf(m_run[r], m);
      alpha[r] = __expf(m_run[r] - mn);
      m_run[r] = mn;
    }
#pragma unroll
    for (int j = 0; j < 8; j++)
#pragma unroll
      for (int r = 0; r < 4; r++) li[j][r] = __expf(li[j][r] - m_run[r]);
#pragma unroll
    for (int r = 0; r < 4; r++) {
      float ssum = li[0][r];
#pragma unroll
      for (int j = 1; j < 8; j++) ssum += li[j][r];
#pragma unroll
      for (int k = 1; k <= 8; k <<= 1) ssum += __shfl_xor(ssum, k);
      l_run[r] = l_run[r] * alpha[r] + ssum;
    }
#pragma unroll
    for (int dt = 0; dt < 3; dt++)
#pragma unroll
      for (int r = 0; r < 4; r++) acc_o[dt][r] *= alpha[r];
#pragma unroll
    for (int j = 0; j < 8; j++)
#pragma unroll
      for (int r = 0; r < 4; r++)
        Ps[w][(quad * 4 + r) * 136 + j * 16 + lane16] = f2b(li[j][r]);
    // O += P V   (3 d-tiles x 4 k-steps)
#pragma unroll
    for (int ks = 0; ks < 4; ks++) {
      bfrag ap = *(const bfrag*)&Ps[w][lane16 * 136 + ks * 32 + quad * 8];
#pragma unroll
      for (int dt = 0; dt < 3; dt++) {
        bfrag bv = *(const bfrag*)&Vs[(dt * 16 + lane16) * 136 + ks * 32 + quad * 8];
        acc_o[dt] = MFMA16(ap, bv, acc_o[dt]);
      }
    }
  }
  float inv[4];
#pragma unroll
  for (int r = 0; r < 4; r++) inv[r] = 1.f / l_run[r];
#pragma unroll
  for (int dt = 0; dt < 3; dt++)
#pragma unroll
    for (int r = 0; r < 4; r++)
      oX[(size_t)(q0 + w * 16 + quad * 4 + r) * DT + h * HDT + dt * 16 + lane16] =
          acc_o[dt][r] * inv[r];
}

// ---------------------------- out = (o .* g) @ o_w via bf16 MFMA, 64x64 tiles
__global__ __launch_bounds__(256) void outproj_kernel(
    const float* __restrict__ oX, const short* __restrict__ gb,
    const short* __restrict__ owt, float* __restrict__ out) {
  __shared__ short As[64 * KP];
  __shared__ short Bs[64 * KP];
  const int t = threadIdx.x;
  const int N0 = blockIdx.x * 64;
  const int M0 = blockIdx.y * 64;
  const int w = t >> 6, l = t & 63;
  const int wm = (w >> 1) * 32, wn = (w & 1) * 32;
  const int lane16 = l & 15, quad = l >> 4;
  ffrag acc[2][2] = {};
  const int srow = t >> 2;          // 0..63
  const int sc = (t & 3) * 16;      // elem offset 0/16/32/48
  for (int k0 = 0; k0 < DT; k0 += 64) {
    uint4 apk[2], bvv[2];
    const float* op = &oX[(size_t)(M0 + srow) * DT + k0 + sc];
    const short* gp = &gb[(size_t)(M0 + srow) * DT + k0 + sc];
    const short* bp = &owt[(size_t)(N0 + srow) * DT + k0 + sc];
#pragma unroll
    for (int i = 0; i < 2; i++) {
      float4 o0 = *(const float4*)&op[i * 8 + 0];
      float4 o1 = *(const float4*)&op[i * 8 + 4];
      union { uint4 u; short s2[8]; } gv;
      gv.u = *(const uint4*)&gp[i * 8];
      union { uint4 u; short s2[8]; } pk;
      float go[8] = {o0.x, o0.y, o0.z, o0.w, o1.x, o1.y, o1.z, o1.w};
#pragma unroll
      for (int jj = 0; jj < 8; jj++) pk.s2[jj] = f2b(go[jj] * b2f(gv.s2[jj]));
      apk[i] = pk.u;
      bvv[i] = *(const uint4*)&bp[i * 8];
    }
    __syncthreads();
    *(uint4*)&As[srow * KP + sc] = apk[0];
    *(uint4*)&As[srow * KP + sc + 8] = apk[1];
    *(uint4*)&Bs[srow * KP + sc] = bvv[0];
    *(uint4*)&Bs[srow * KP + sc + 8] = bvv[1];
    __syncthreads();
#pragma unroll
    for (int ks = 0; ks < 2; ks++) {
      bfrag a[2], b[2];
#pragma unroll
      for (int i = 0; i < 2; i++)
        a[i] = *(const bfrag*)&As[(wm + i * 16 + lane16) * KP + ks * 32 + quad * 8];
#pragma unroll
      for (int j = 0; j < 2; j++)
        b[j] = *(const bfrag*)&Bs[(wn + j * 16 + lane16) * KP + ks * 32 + quad * 8];
#pragma unroll
      for (int i = 0; i < 2; i++)
#pragma unroll
        for (int j = 0; j < 2; j++) acc[i][j] = MFMA16(a[i], b[j], acc[i][j]);
    }
  }
#pragma unroll
  for (int i = 0; i < 2; i++)
#pragma unroll
    for (int j = 0; j < 2; j++) {
      int n = N0 + wn + j * 16 + lane16;
#pragma unroll
      for (int r = 0; r < 4; r++) {
        int m = M0 + wm + i * 16 + quad * 4 + r;
        out[(size_t)m * DT + n] = acc[i][j][r];
      }
    }
}

extern "C" void kernel_launch(void* const* d_in, const int* in_sizes, int n_in,
                              void* d_out, int out_size, void* d_ws,
                              size_t ws_size, hipStream_t stream) {
  const float* s = (const float*)d_in[0];
  const float* z = (const float*)d_in[1];
  const float* nsw = (const float*)d_in[2];
  const float* nsb = (const float*)d_in[3];
  const float* qw = (const float*)d_in[4];
  const float* qbias = (const float*)d_in[5];
  const float* kw = (const float*)d_in[6];
  const float* vw = (const float*)d_in[7];
  const float* gw = (const float*)d_in[8];
  const float* znw = (const float*)d_in[9];
  const float* znb = (const float*)d_in[10];
  const float* zww = (const float*)d_in[11];
  const float* ow = (const float*)d_in[12];
  float* out = (float*)d_out;
  char* W = (char*)d_ws;

  short* biasb = (short*)W;                        // 18,874,368 B
  short* snb = (short*)(W + 18874368);             // 1,179,648 B
  short* qb = (short*)(W + 20054016);
  short* kb = (short*)(W + 21233664);
  short* gb = (short*)(W + 22413312);
  short* vT = (short*)(W + 23592960);
  short* wt = (short*)(W + 24772608);              // 5 x 1,179,648 B
  float* oX = (float*)(W + 30670848);              // 2,359,296 B
  short* w1th = (short*)(W + 33030144);            // 4096 B
  short* w1tl = (short*)(W + 33034240);            // 4096 B
  float* wcs = (float*)(W + 33038336);             // 64 B
  float* bh = (float*)(W + 33038400);              // 64 B

  // setup -> proj -> zbias(nt loads) -> attn -> outproj
  setup_kernel<<<1489, 256, 0, stream>>>(s, nsw, nsb, snb, qw, kw, vw, gw, ow,
                                         wt, znw, znb, zww, w1th, w1tl, wcs,
                                         bh);
  proj_kernel<<<dim3(6, 6, 4), 256, 0, stream>>>(snb, wt, qbias, qb, kb, vT,
                                                 gb);
  zbias_kernel<<<2304, 256, 0, stream>>>(z, w1th, w1tl, wcs, bh, biasb);
  attn_kernel<<<dim3(12, 16), 256, 0, stream>>>(qb, kb, vT, biasb, oX);
  outproj_kernel<<<dim3(12, 12), 256, 0, stream>>>(oX, gb, wt + 4 * (size_t)NN,
                                                   out);
}

// Round 6
// 525.104 us; speedup vs baseline: 1.1862x; 1.0354x over previous
//
#include <hip/hip_runtime.h>
#include <math.h>

constexpr int NT = 768;      // sequence length N
constexpr int DT = 768;      // model dim D
constexpr int HT = 16;       // heads
constexpr int HDT = 48;      // head dim
constexpr int ZDT = 128;     // pair-rep dim
constexpr int NN = NT * NT;  // 589824
constexpr float LN_EPS = 1e-5f;
constexpr float SCALE = 0.14433756729740643f;  // 48^-0.5
constexpr int KP = 72;       // LDS k-stride in bf16 elems (64 + 8 pad)

typedef __attribute__((ext_vector_type(8))) short bfrag;   // 8 bf16 (4 VGPR)
typedef __attribute__((ext_vector_type(4))) float ffrag;   // 4 fp32 acc
typedef __attribute__((ext_vector_type(4))) float f4;      // clang ext-vector

#define MFMA16(a, b, c) __builtin_amdgcn_mfma_f32_16x16x32_bf16(a, b, c, 0, 0, 0)

__device__ __forceinline__ short f2b(float f) {
  unsigned u = __builtin_bit_cast(unsigned, f);
  u += 0x7fffu + ((u >> 16) & 1u);   // RNE
  return (short)(u >> 16);
}
__device__ __forceinline__ float b2f(short s) {
  return __builtin_bit_cast(float, (unsigned)(unsigned short)s << 16);
}
// hi/lo bf16 split by truncation: hi16(f)+lo16(f) reconstructs f to ~2^-24 rel
__device__ __forceinline__ short hi16(float f) {
  return (short)(__builtin_bit_cast(unsigned, f) >> 16);
}
__device__ __forceinline__ short lo16(float f) {
  unsigned u = __builtin_bit_cast(unsigned, f);
  float r = f - __builtin_bit_cast(float, u & 0xffff0000u);  // exact in fp32
  return (short)(__builtin_bit_cast(unsigned, r) >> 16);
}
__device__ __forceinline__ float s4v(f4 v) { return (v.x + v.y) + (v.z + v.w); }
__device__ __forceinline__ float q4v(f4 v) {
  return (v.x * v.x + v.y * v.y) + (v.z * v.z + v.w * v.w);
}

// ---------------------------------------------------------------------------
// setup: fused  prep (blocks 0..719)  |  ln_s (720..1487)  |  zsetup (1488)
// ---------------------------------------------------------------------------
__global__ __launch_bounds__(256) void setup_kernel(
    const float* __restrict__ s, const float* __restrict__ nsw,
    const float* __restrict__ nsb, short* __restrict__ snb,
    const float* __restrict__ qw, const float* __restrict__ kw,
    const float* __restrict__ vw, const float* __restrict__ gw,
    const float* __restrict__ ow, short* __restrict__ wt,
    const float* __restrict__ znw, const float* __restrict__ znb,
    const float* __restrict__ zw, short* __restrict__ w1th,
    short* __restrict__ w1tl, float* __restrict__ wcs,
    float* __restrict__ bh) {
  const int bid = blockIdx.x;
  const int t = threadIdx.x;
  if (bid < 720) {
    // ---------------- prep branch (x=n-tile, y=k-tile, z=which flattened)
    __shared__ float Ts[64][65];
    const int which = bid / 144;
    const int rem = bid % 144;
    const int k0 = (rem / 12) * 64;
    const int n0 = (rem % 12) * 64;
    const float* src = which == 0 ? qw : which == 1 ? kw : which == 2 ? vw
                       : which == 3 ? gw : ow;
    short* dst = wt + (size_t)which * NN;
    const int r = t >> 4, c = (t & 15) * 4;
#pragma unroll
    for (int i = 0; i < 4; i++) {
      int rr = r + i * 16;
      float4 v = *(const float4*)&src[(size_t)(k0 + rr) * DT + n0 + c];
      Ts[rr][c + 0] = v.x; Ts[rr][c + 1] = v.y;
      Ts[rr][c + 2] = v.z; Ts[rr][c + 3] = v.w;
    }
    __syncthreads();
#pragma unroll
    for (int i = 0; i < 2; i++) {
      int cid = t + i * 256;          // 512 chunks of 8
      int nr = cid >> 3, kc = cid & 7;
      union { uint4 u; short s2[8]; } pk;
#pragma unroll
      for (int j = 0; j < 8; j++) pk.s2[j] = f2b(Ts[kc * 8 + j][nr]);
      *(uint4*)&dst[(size_t)(n0 + nr) * DT + k0 + kc * 8] = pk.u;
    }
  } else if (bid < 1488) {
    // ---------------- ln_s branch
    const int row = bid - 720;
    const float* x = s + row * DT;
    float v0 = x[t], v1 = x[t + 256], v2 = x[t + 512];
    float sum = v0 + v1 + v2;
    float sq = v0 * v0 + v1 * v1 + v2 * v2;
#pragma unroll
    for (int off = 32; off; off >>= 1) {
      sum += __shfl_xor(sum, off);
      sq += __shfl_xor(sq, off);
    }
    __shared__ float ls[4], lq[4], stats[2];
    const int wid = t >> 6;
    if ((t & 63) == 0) { ls[wid] = sum; lq[wid] = sq; }
    __syncthreads();
    if (t == 0) {
      float S = ls[0] + ls[1] + ls[2] + ls[3];
      float Q = lq[0] + lq[1] + lq[2] + lq[3];
      float mu = S * (1.f / DT);
      float var = Q * (1.f / DT) - mu * mu;
      stats[0] = mu;
      stats[1] = rsqrtf(var + LN_EPS);
    }
    __syncthreads();
    const float mu = stats[0], rs = stats[1];
    short* y = snb + row * DT;
    y[t] = f2b((v0 - mu) * rs * nsw[t] + nsb[t]);
    y[t + 256] = f2b((v1 - mu) * rs * nsw[t + 256] + nsb[t + 256]);
    y[t + 512] = f2b((v2 - mu) * rs * nsw[t + 512] + nsb[t + 512]);
  } else {
    // ---------------- zsetup branch
    __shared__ float sm[ZDT * HT];     // w1[c][h] = znw[c] * zw[c][h]
#pragma unroll
    for (int i = 0; i < 8; i++) {
      int idx = t * 8 + i;
      int c = idx >> 4;
      sm[idx] = znw[c] * zw[idx];
    }
    __syncthreads();
#pragma unroll
    for (int i = 0; i < 8; i++) {
      int idx = t * 8 + i;
      int c = idx >> 4, h = idx & 15;
      float v = sm[idx];
      short hi = f2b(v);
      w1th[h * ZDT + c] = hi;                 // W^T hi (bf16)
      w1tl[h * ZDT + c] = f2b(v - b2f(hi));   // W^T lo residual (bf16)
    }
    if (t < HT) {
      float s1 = 0.f, s2 = 0.f;
      for (int c = 0; c < ZDT; c++) s1 += sm[c * HT + t];
      wcs[t] = s1;                            // column sums of w1
      for (int c = 0; c < ZDT; c++) s2 += znb[c] * zw[c * HT + t];
      bh[t] = s2;                             // folded LN bias term
    }
  }
}

// ------------------------------- q/k/v/g projections via bf16 MFMA, 128x128
__global__ __launch_bounds__(256) void proj_kernel(
    const short* __restrict__ snb, const short* __restrict__ wt,
    const float* __restrict__ qbias, short* __restrict__ qb,
    short* __restrict__ kb, short* __restrict__ vT, short* __restrict__ gb) {
  __shared__ short As[128 * KP];
  __shared__ short Bs[128 * KP];
  const int t = threadIdx.x;
  const int which = blockIdx.z;
  const short* W = wt + (size_t)which * NN;
  const int N0 = blockIdx.x * 128;
  const int M0 = blockIdx.y * 128;
  const int w = t >> 6, l = t & 63;
  const int wm = (w >> 1) * 64, wn = (w & 1) * 64;
  const int lane16 = l & 15, quad = l >> 4;
  ffrag acc[4][4] = {};
  const int srow = t >> 3, skc = t & 7;
  for (int k0 = 0; k0 < DT; k0 += 64) {
    uint4 av[4], bv[4];
#pragma unroll
    for (int i = 0; i < 4; i++) {
      int row = srow + i * 32;
      av[i] = *(const uint4*)&snb[(size_t)(M0 + row) * DT + k0 + skc * 8];
      bv[i] = *(const uint4*)&W[(size_t)(N0 + row) * DT + k0 + skc * 8];
    }
    __syncthreads();
#pragma unroll
    for (int i = 0; i < 4; i++) {
      int row = srow + i * 32;
      *(uint4*)&As[row * KP + skc * 8] = av[i];
      *(uint4*)&Bs[row * KP + skc * 8] = bv[i];
    }
    __syncthreads();
#pragma unroll
    for (int ks = 0; ks < 2; ks++) {
      bfrag a[4], b[4];
#pragma unroll
      for (int i = 0; i < 4; i++)
        a[i] = *(const bfrag*)&As[(wm + i * 16 + lane16) * KP + ks * 32 + quad * 8];
#pragma unroll
      for (int j = 0; j < 4; j++)
        b[j] = *(const bfrag*)&Bs[(wn + j * 16 + lane16) * KP + ks * 32 + quad * 8];
#pragma unroll
      for (int i = 0; i < 4; i++)
#pragma unroll
        for (int j = 0; j < 4; j++) acc[i][j] = MFMA16(a[i], b[j], acc[i][j]);
    }
    __syncthreads();
  }
#pragma unroll
  for (int i = 0; i < 4; i++) {
#pragma unroll
    for (int j = 0; j < 4; j++) {
      int n = N0 + wn + j * 16 + lane16;
#pragma unroll
      for (int r = 0; r < 4; r++) {
        int m = M0 + wm + i * 16 + quad * 4 + r;
        float v = acc[i][j][r];
        if (which == 0) {
          qb[(size_t)m * DT + n] = f2b(v + qbias[n]);
        } else if (which == 1) {
          kb[(size_t)m * DT + n] = f2b(v);
        } else if (which == 2) {
          vT[(size_t)n * NT + m] = f2b(v);   // [h*48+d][seq] for AV B-operand
        } else {
          gb[(size_t)m * DT + n] = f2b(1.f / (1.f + __expf(-v)));
        }
      }
    }
  }
}

// ---------------------------------------------------------------------------
// zbias v6 = v5 with COALESCED z loads (single-variable change vs v5).
// v5's loads were intra-wave scattered: each instr touched 16 rows x 16 B
// (32 half-used lines). v6: each load instr covers 1 KB contiguous
// (lane l -> byte l*16), staged via a per-wave 8 KB LDS slice with XOR-by-row
// swizzle (chunk ^ (row&7)) so frag reads are conflict-free (linear-profile).
// Same-wave ds_write -> ds_read is in-order (DS FIFO per wave): no barrier.
// Everything downstream of the 8 f4s is byte-identical to v5.
// ---------------------------------------------------------------------------
__global__ __launch_bounds__(256) void zbias_kernel(
    const float* __restrict__ z, const short* __restrict__ w1th,
    const short* __restrict__ w1tl, const float* __restrict__ wcs,
    const float* __restrict__ bh, short* __restrict__ biasb) {
  __shared__ f4 Zs[4][16 * 32];   // per-wave 8 KB staging (4 waves)
  const int t = threadIdx.x;
  const int w = t >> 6, l = t & 63;
  const int lane16 = l & 15, quad = l >> 4;
  // loop-invariant B-frags: W^T[h=lane16][k], hi/lo, 4 k-steps (32 VGPR)
  const bfrag wh0 = *(const bfrag*)&w1th[lane16 * ZDT + 0 + quad * 8];
  const bfrag wh1 = *(const bfrag*)&w1th[lane16 * ZDT + 32 + quad * 8];
  const bfrag wh2 = *(const bfrag*)&w1th[lane16 * ZDT + 64 + quad * 8];
  const bfrag wh3 = *(const bfrag*)&w1th[lane16 * ZDT + 96 + quad * 8];
  const bfrag wl0 = *(const bfrag*)&w1tl[lane16 * ZDT + 0 + quad * 8];
  const bfrag wl1 = *(const bfrag*)&w1tl[lane16 * ZDT + 32 + quad * 8];
  const bfrag wl2 = *(const bfrag*)&w1tl[lane16 * ZDT + 64 + quad * 8];
  const bfrag wl3 = *(const bfrag*)&w1tl[lane16 * ZDT + 96 + quad * 8];
  const float wcs_h = wcs[lane16];
  const float bh_h = bh[lane16];
  const int row_base0 = blockIdx.x * 256 + w * 64;
  f4* zs = Zs[w];
  const int lh = l >> 5, lc = l & 31;           // write-side: sub-row, chunk
  const int rsw = lane16 * 32, rx = lane16 & 7; // read-side: row base, xor key
#pragma unroll
  for (int it = 0; it < 4; it++) {
    const int rbase = row_base0 + it * 16;
    // 8 coalesced nt loads: instr i covers bytes [i*1KB, i*1KB+1KB)
    const f4* ztile = (const f4*)&z[(size_t)rbase * ZDT];
    const f4 g0 = __builtin_nontemporal_load(ztile + 0 * 64 + l);
    const f4 g1 = __builtin_nontemporal_load(ztile + 1 * 64 + l);
    const f4 g2 = __builtin_nontemporal_load(ztile + 2 * 64 + l);
    const f4 g3 = __builtin_nontemporal_load(ztile + 3 * 64 + l);
    const f4 g4 = __builtin_nontemporal_load(ztile + 4 * 64 + l);
    const f4 g5 = __builtin_nontemporal_load(ztile + 5 * 64 + l);
    const f4 g6 = __builtin_nontemporal_load(ztile + 6 * 64 + l);
    const f4 g7 = __builtin_nontemporal_load(ztile + 7 * 64 + l);
    // swizzled LDS writes: chunk g=i*64+l -> row=i*2+lh, c=lc, idx=row*32+(c^(row&7))
    zs[(0 * 2 + lh) * 32 + (lc ^ ((0 * 2 + lh) & 7))] = g0;
    zs[(1 * 2 + lh) * 32 + (lc ^ ((1 * 2 + lh) & 7))] = g1;
    zs[(2 * 2 + lh) * 32 + (lc ^ ((2 * 2 + lh) & 7))] = g2;
    zs[(3 * 2 + lh) * 32 + (lc ^ ((3 * 2 + lh) & 7))] = g3;
    zs[(4 * 2 + lh) * 32 + (lc ^ ((4 * 2 + lh) & 7))] = g4;
    zs[(5 * 2 + lh) * 32 + (lc ^ ((5 * 2 + lh) & 7))] = g5;
    zs[(6 * 2 + lh) * 32 + (lc ^ ((6 * 2 + lh) & 7))] = g6;
    zs[(7 * 2 + lh) * 32 + (lc ^ ((7 * 2 + lh) & 7))] = g7;
    // swizzled frag reads: lane(r=lane16,q=quad) -> row r chunks
    // {2q,2q+1, +8, +16, +24} = floats q*8+{0..7} of each 32-float k-block
    const f4 a0 = zs[rsw + ((2 * quad + 0) ^ rx)];
    const f4 b0 = zs[rsw + ((2 * quad + 1) ^ rx)];
    const f4 a1 = zs[rsw + ((2 * quad + 8) ^ rx)];
    const f4 b1 = zs[rsw + ((2 * quad + 9) ^ rx)];
    const f4 a2 = zs[rsw + ((2 * quad + 16) ^ rx)];
    const f4 b2 = zs[rsw + ((2 * quad + 17) ^ rx)];
    const f4 a3 = zs[rsw + ((2 * quad + 24) ^ rx)];
    const f4 b3 = zs[rsw + ((2 * quad + 25) ^ rx)];
    // row stats (this lane holds 32 of 128 elems; combine the 4 quads)
    float sum = ((s4v(a0) + s4v(b0)) + (s4v(a1) + s4v(b1))) +
                ((s4v(a2) + s4v(b2)) + (s4v(a3) + s4v(b3)));
    float sq = ((q4v(a0) + q4v(b0)) + (q4v(a1) + q4v(b1))) +
               ((q4v(a2) + q4v(b2)) + (q4v(a3) + q4v(b3)));
    sum += __shfl_xor(sum, 16); sq += __shfl_xor(sq, 16);
    sum += __shfl_xor(sum, 32); sq += __shfl_xor(sq, 32);
    // truncation hi/lo split, built directly into frag lanes
    const bfrag xh0 = {hi16(a0.x), hi16(a0.y), hi16(a0.z), hi16(a0.w),
                       hi16(b0.x), hi16(b0.y), hi16(b0.z), hi16(b0.w)};
    const bfrag xl0 = {lo16(a0.x), lo16(a0.y), lo16(a0.z), lo16(a0.w),
                       lo16(b0.x), lo16(b0.y), lo16(b0.z), lo16(b0.w)};
    const bfrag xh1 = {hi16(a1.x), hi16(a1.y), hi16(a1.z), hi16(a1.w),
                       hi16(b1.x), hi16(b1.y), hi16(b1.z), hi16(b1.w)};
    const bfrag xl1 = {lo16(a1.x), lo16(a1.y), lo16(a1.z), lo16(a1.w),
                       lo16(b1.x), lo16(b1.y), lo16(b1.z), lo16(b1.w)};
    const bfrag xh2 = {hi16(a2.x), hi16(a2.y), hi16(a2.z), hi16(a2.w),
                       hi16(b2.x), hi16(b2.y), hi16(b2.z), hi16(b2.w)};
    const bfrag xl2 = {lo16(a2.x), lo16(a2.y), lo16(a2.z), lo16(a2.w),
                       lo16(b2.x), lo16(b2.y), lo16(b2.z), lo16(b2.w)};
    const bfrag xh3 = {hi16(a3.x), hi16(a3.y), hi16(a3.z), hi16(a3.w),
                       hi16(b3.x), hi16(b3.y), hi16(b3.z), hi16(b3.w)};
    const bfrag xl3 = {lo16(a3.x), lo16(a3.y), lo16(a3.z), lo16(a3.w),
                       lo16(b3.x), lo16(b3.y), lo16(b3.z), lo16(b3.w)};
    // 3 independent accumulation chains (4 MFMAs each)
    ffrag accA = {0.f, 0.f, 0.f, 0.f};   // xh * Wh
    ffrag accB = {0.f, 0.f, 0.f, 0.f};   // xl * Wh
    ffrag accC = {0.f, 0.f, 0.f, 0.f};   // xh * Wl
    accA = MFMA16(xh0, wh0, accA);
    accB = MFMA16(xl0, wh0, accB);
    accC = MFMA16(xh0, wl0, accC);
    accA = MFMA16(xh1, wh1, accA);
    accB = MFMA16(xl1, wh1, accB);
    accC = MFMA16(xh1, wl1, accC);
    accA = MFMA16(xh2, wh2, accA);
    accB = MFMA16(xl2, wh2, accB);
    accC = MFMA16(xh2, wl2, accC);
    accA = MFMA16(xh3, wh3, accA);
    accB = MFMA16(xl3, wh3, accB);
    accC = MFMA16(xh3, wl3, accC);
    // epilogue: C[row=quad*4+r][h=lane16]; row stats fetched by shuffle
    union { uint2 u; short s2[4]; } pk;
#pragma unroll
    for (int r = 0; r < 4; r++) {
      float rsum = __shfl(sum, quad * 4 + r);
      float rsq = __shfl(sq, quad * 4 + r);
      float mu = rsum * (1.f / 128.f);
      float rs = rsqrtf(rsq * (1.f / 128.f) - mu * mu + LN_EPS);
      float av = (accA[r] + accB[r]) + accC[r];
      pk.s2[r] = f2b(rs * (av - mu * wcs_h) + bh_h);
    }
    *(uint2*)&biasb[(size_t)lane16 * NN + rbase + quad * 4] = pk.u;
  }
}

// ------- fused attention: S=QK^T*scale+bias, online softmax, O=PV
// grid (12 q-tiles of 64, 16 heads); 4 waves, wave w owns q-rows w*16..+16
__global__ __launch_bounds__(256) void attn_kernel(
    const short* __restrict__ qb, const short* __restrict__ kb,
    const short* __restrict__ vT, const short* __restrict__ biasb,
    float* __restrict__ oX) {
  __shared__ short Ks[128 * 48];       // [kpos][d]
  __shared__ short Vs[48 * 136];       // [d][kpos+8 pad]
  __shared__ short Ps[4][16 * 136];    // per-wave private P slice
  const int t = threadIdx.x;
  const int h = blockIdx.y;
  const int q0 = blockIdx.x * 64;
  const int w = t >> 6, l = t & 63;
  const int lane16 = l & 15, quad = l >> 4;
  const int qrow = q0 + w * 16 + lane16;
  bfrag a_q0 = *(const bfrag*)&qb[(size_t)qrow * DT + h * HDT + quad * 8];
  bfrag a_q1 = {0, 0, 0, 0, 0, 0, 0, 0};   // k 48..63 zero-padded
  if (quad < 2)
    a_q1 = *(const bfrag*)&qb[(size_t)qrow * DT + h * HDT + 32 + quad * 8];
  const int koff1 = (quad < 2) ? (32 + quad * 8) : 0;
  ffrag acc_o[3] = {};
  float m_run[4] = {-1e30f, -1e30f, -1e30f, -1e30f};
  float l_run[4] = {};
  const size_t bias_base =
      (size_t)h * NN + (size_t)(q0 + w * 16 + quad * 4) * NT + lane16;
  for (int kt = 0; kt < 6; kt++) {
    const int k0 = kt * 128;
    uint4 kv[3], vv[3];
#pragma unroll
    for (int i = 0; i < 3; i++) {
      int cid = t + i * 256;
      int kr = cid / 6, kc = cid % 6;
      kv[i] = *(const uint4*)&kb[(size_t)(k0 + kr) * DT + h * HDT + kc * 8];
      int vr = cid >> 4, vc = cid & 15;
      vv[i] = *(const uint4*)&vT[((size_t)h * HDT + vr) * NT + k0 + vc * 8];
    }
    short bias_s[8][4];
#pragma unroll
    for (int j = 0; j < 8; j++)
#pragma unroll
      for (int r = 0; r < 4; r++)
        bias_s[j][r] = biasb[bias_base + (size_t)r * NT + k0 + j * 16];
    __syncthreads();
#pragma unroll
    for (int i = 0; i < 3; i++) {
      int cid = t + i * 256;
      int kr = cid / 6, kc = cid % 6;
      *(uint4*)&Ks[kr * 48 + kc * 8] = kv[i];
      int vr = cid >> 4, vc = cid & 15;
      *(uint4*)&Vs[vr * 136 + vc * 8] = vv[i];
    }
    __syncthreads();
    // S = Q K^T   (8 n-tiles x 2 k-steps)
    ffrag sc[8];
#pragma unroll
    for (int j = 0; j < 8; j++) {
      ffrag zf = {0.f, 0.f, 0.f, 0.f};
      bfrag b0 = *(const bfrag*)&Ks[(j * 16 + lane16) * 48 + quad * 8];
      bfrag b1 = *(const bfrag*)&Ks[(j * 16 + lane16) * 48 + koff1];
      zf = MFMA16(a_q0, b0, zf);
      sc[j] = MFMA16(a_q1, b1, zf);
    }
    // logits + online softmax (C layout: col=lane16, row=quad*4+r)
    float li[8][4];
#pragma unroll
    for (int j = 0; j < 8; j++)
#pragma unroll
      for (int r = 0; r < 4; r++)
        li[j][r] = sc[j][r] * SCALE + b2f(bias_s[j][r]);
    float alpha[4];
#pragma unroll
    for (int r = 0; r < 4; r++) {
      float m = li[0][r];
#pragma unroll
      for (int j = 1; j < 8; j++) m = fmaxf(m, li[j][r]);
#pragma unroll
      for (int k = 1; k <= 8; k <<= 1) m = fmaxf(m, __shfl_xor(m, k));
      float mn = fmaxf(m_run[r], m);
      alpha[r] = __expf(m_run[r] - mn);
      m_run[r] = mn;
    }
#pragma unroll
    for (int j = 0; j < 8; j++)
#pragma unroll
      for (int r = 0; r < 4; r++) li[j][r] = __expf(li[j][r] - m_run[r]);
#pragma unroll
    for (int r = 0; r < 4; r++) {
      float ssum = li[0][r];
#pragma unroll
      for (int j = 1; j < 8; j++) ssum += li[j][r];
#pragma unroll
      for (int k = 1; k <= 8; k <<= 1) ssum += __shfl_xor(ssum, k);
      l_run[r] = l_run[r] * alpha[r] + ssum;
    }
#pragma unroll
    for (int dt = 0; dt < 3; dt++)
#pragma unroll
      for (int r = 0; r < 4; r++) acc_o[dt][r] *= alpha[r];
#pragma unroll
    for (int j = 0; j < 8; j++)
#pragma unroll
      for (int r = 0; r < 4; r++)
        Ps[w][(quad * 4 + r) * 136 + j * 16 + lane16] = f2b(li[j][r]);
    // O += P V   (3 d-tiles x 4 k-steps)
#pragma unroll
    for (int ks = 0; ks < 4; ks++) {
      bfrag ap = *(const bfrag*)&Ps[w][lane16 * 136 + ks * 32 + quad * 8];
#pragma unroll
      for (int dt = 0; dt < 3; dt++) {
        bfrag bv = *(const bfrag*)&Vs[(dt * 16 + lane16) * 136 + ks * 32 + quad * 8];
        acc_o[dt] = MFMA16(ap, bv, acc_o[dt]);
      }
    }
  }
  float inv[4];
#pragma unroll
  for (int r = 0; r < 4; r++) inv[r] = 1.f / l_run[r];
#pragma unroll
  for (int dt = 0; dt < 3; dt++)
#pragma unroll
    for (int r = 0; r < 4; r++)
      oX[(size_t)(q0 + w * 16 + quad * 4 + r) * DT + h * HDT + dt * 16 + lane16] =
          acc_o[dt][r] * inv[r];
}

// ---------------------------- out = (o .* g) @ o_w via bf16 MFMA, 64x64 tiles
__global__ __launch_bounds__(256) void outproj_kernel(
    const float* __restrict__ oX, const short* __restrict__ gb,
    const short* __restrict__ owt, float* __restrict__ out) {
  __shared__ short As[64 * KP];
  __shared__ short Bs[64 * KP];
  const int t = threadIdx.x;
  const int N0 = blockIdx.x * 64;
  const int M0 = blockIdx.y * 64;
  const int w = t >> 6, l = t & 63;
  const int wm = (w >> 1) * 32, wn = (w & 1) * 32;
  const int lane16 = l & 15, quad = l >> 4;
  ffrag acc[2][2] = {};
  const int srow = t >> 2;          // 0..63
  const int sc = (t & 3) * 16;      // elem offset 0/16/32/48
  for (int k0 = 0; k0 < DT; k0 += 64) {
    uint4 apk[2], bvv[2];
    const float* op = &oX[(size_t)(M0 + srow) * DT + k0 + sc];
    const short* gp = &gb[(size_t)(M0 + srow) * DT + k0 + sc];
    const short* bp = &owt[(size_t)(N0 + srow) * DT + k0 + sc];
#pragma unroll
    for (int i = 0; i < 2; i++) {
      float4 o0 = *(const float4*)&op[i * 8 + 0];
      float4 o1 = *(const float4*)&op[i * 8 + 4];
      union { uint4 u; short s2[8]; } gv;
      gv.u = *(const uint4*)&gp[i * 8];
      union { uint4 u; short s2[8]; } pk;
      float go[8] = {o0.x, o0.y, o0.z, o0.w, o1.x, o1.y, o1.z, o1.w};
#pragma unroll
      for (int jj = 0; jj < 8; jj++) pk.s2[jj] = f2b(go[jj] * b2f(gv.s2[jj]));
      apk[i] = pk.u;
      bvv[i] = *(const uint4*)&bp[i * 8];
    }
    __syncthreads();
    *(uint4*)&As[srow * KP + sc] = apk[0];
    *(uint4*)&As[srow * KP + sc + 8] = apk[1];
    *(uint4*)&Bs[srow * KP + sc] = bvv[0];
    *(uint4*)&Bs[srow * KP + sc + 8] = bvv[1];
    __syncthreads();
#pragma unroll
    for (int ks = 0; ks < 2; ks++) {
      bfrag a[2], b[2];
#pragma unroll
      for (int i = 0; i < 2; i++)
        a[i] = *(const bfrag*)&As[(wm + i * 16 + lane16) * KP + ks * 32 + quad * 8];
#pragma unroll
      for (int j = 0; j < 2; j++)
        b[j] = *(const bfrag*)&Bs[(wn + j * 16 + lane16) * KP + ks * 32 + quad * 8];
#pragma unroll
      for (int i = 0; i < 2; i++)
#pragma unroll
        for (int j = 0; j < 2; j++) acc[i][j] = MFMA16(a[i], b[j], acc[i][j]);
    }
  }
#pragma unroll
  for (int i = 0; i < 2; i++)
#pragma unroll
    for (int j = 0; j < 2; j++) {
      int n = N0 + wn + j * 16 + lane16;
#pragma unroll
      for (int r = 0; r < 4; r++) {
        int m = M0 + wm + i * 16 + quad * 4 + r;
        out[(size_t)m * DT + n] = acc[i][j][r];
      }
    }
}

extern "C" void kernel_launch(void* const* d_in, const int* in_sizes, int n_in,
                              void* d_out, int out_size, void* d_ws,
                              size_t ws_size, hipStream_t stream) {
  const float* s = (const float*)d_in[0];
  const float* z = (const float*)d_in[1];
  const float* nsw = (const float*)d_in[2];
  const float* nsb = (const float*)d_in[3];
  const float* qw = (const float*)d_in[4];
  const float* qbias = (const float*)d_in[5];
  const float* kw = (const float*)d_in[6];
  const float* vw = (const float*)d_in[7];
  const float* gw = (const float*)d_in[8];
  const float* znw = (const float*)d_in[9];
  const float* znb = (const float*)d_in[10];
  const float* zww = (const float*)d_in[11];
  const float* ow = (const float*)d_in[12];
  float* out = (float*)d_out;
  char* W = (char*)d_ws;

  short* biasb = (short*)W;                        // 18,874,368 B
  short* snb = (short*)(W + 18874368);             // 1,179,648 B
  short* qb = (short*)(W + 20054016);
  short* kb = (short*)(W + 21233664);
  short* gb = (short*)(W + 22413312);
  short* vT = (short*)(W + 23592960);
  short* wt = (short*)(W + 24772608);              // 5 x 1,179,648 B
  float* oX = (float*)(W + 30670848);              // 2,359,296 B
  short* w1th = (short*)(W + 33030144);            // 4096 B
  short* w1tl = (short*)(W + 33034240);            // 4096 B
  float* wcs = (float*)(W + 33038336);             // 64 B
  float* bh = (float*)(W + 33038400);              // 64 B

  // setup -> proj -> zbias(coalesced+LDS swz) -> attn -> outproj
  setup_kernel<<<1489, 256, 0, stream>>>(s, nsw, nsb, snb, qw, kw, vw, gw, ow,
                                         wt, znw, znb, zww, w1th, w1tl, wcs,
                                         bh);
  proj_kernel<<<dim3(6, 6, 4), 256, 0, stream>>>(snb, wt, qbias, qb, kb, vT,
                                                 gb);
  zbias_kernel<<<2304, 256, 0, stream>>>(z, w1th, w1tl, wcs, bh, biasb);
  attn_kernel<<<dim3(12, 16), 256, 0, stream>>>(qb, kb, vT, biasb, oX);
  outproj_kernel<<<dim3(12, 12), 256, 0, stream>>>(oX, gb, wt + 4 * (size_t)NN,
                                                   out);
}

// Round 7
// 491.110 us; speedup vs baseline: 1.2683x; 1.0692x over previous
//
#include <hip/hip_runtime.h>
#include <math.h>

constexpr int NT = 768;      // sequence length N
constexpr int DT = 768;      // model dim D
constexpr int HT = 16;       // heads
constexpr int HDT = 48;      // head dim
constexpr int ZDT = 128;     // pair-rep dim
constexpr int NN = NT * NT;  // 589824
constexpr float LN_EPS = 1e-5f;
constexpr float SCALE = 0.14433756729740643f;  // 48^-0.5
constexpr int KP = 72;       // LDS k-stride in bf16 elems (64 + 8 pad)

typedef __attribute__((ext_vector_type(8))) short bfrag;   // 8 bf16 (4 VGPR)
typedef __attribute__((ext_vector_type(4))) float ffrag;   // 4 fp32 acc
typedef __attribute__((ext_vector_type(4))) float f4;      // clang ext-vector

#define MFMA16(a, b, c) __builtin_amdgcn_mfma_f32_16x16x32_bf16(a, b, c, 0, 0, 0)

__device__ __forceinline__ short f2b(float f) {
  unsigned u = __builtin_bit_cast(unsigned, f);
  u += 0x7fffu + ((u >> 16) & 1u);   // RNE
  return (short)(u >> 16);
}
__device__ __forceinline__ float b2f(short s) {
  return __builtin_bit_cast(float, (unsigned)(unsigned short)s << 16);
}
// hi/lo bf16 split by truncation: hi16(f)+lo16(f) reconstructs f to ~2^-24 rel
__device__ __forceinline__ short hi16(float f) {
  return (short)(__builtin_bit_cast(unsigned, f) >> 16);
}
__device__ __forceinline__ short lo16(float f) {
  unsigned u = __builtin_bit_cast(unsigned, f);
  float r = f - __builtin_bit_cast(float, u & 0xffff0000u);  // exact in fp32
  return (short)(__builtin_bit_cast(unsigned, r) >> 16);
}
__device__ __forceinline__ float s4v(f4 v) { return (v.x + v.y) + (v.z + v.w); }
__device__ __forceinline__ float q4v(f4 v) {
  return (v.x * v.x + v.y * v.y) + (v.z * v.z + v.w * v.w);
}

// ---------------------------------------------------------------------------
// setup: fused  prep (blocks 0..719)  |  ln_s (720..1487)  |  zsetup (1488)
// ---------------------------------------------------------------------------
__global__ __launch_bounds__(256) void setup_kernel(
    const float* __restrict__ s, const float* __restrict__ nsw,
    const float* __restrict__ nsb, short* __restrict__ snb,
    const float* __restrict__ qw, const float* __restrict__ kw,
    const float* __restrict__ vw, const float* __restrict__ gw,
    const float* __restrict__ ow, short* __restrict__ wt,
    const float* __restrict__ znw, const float* __restrict__ znb,
    const float* __restrict__ zw, short* __restrict__ w1th,
    short* __restrict__ w1tl, float* __restrict__ wcs,
    float* __restrict__ bh) {
  const int bid = blockIdx.x;
  const int t = threadIdx.x;
  if (bid < 720) {
    // ---------------- prep branch (x=n-tile, y=k-tile, z=which flattened)
    __shared__ float Ts[64][65];
    const int which = bid / 144;
    const int rem = bid % 144;
    const int k0 = (rem / 12) * 64;
    const int n0 = (rem % 12) * 64;
    const float* src = which == 0 ? qw : which == 1 ? kw : which == 2 ? vw
                       : which == 3 ? gw : ow;
    short* dst = wt + (size_t)which * NN;
    const int r = t >> 4, c = (t & 15) * 4;
#pragma unroll
    for (int i = 0; i < 4; i++) {
      int rr = r + i * 16;
      float4 v = *(const float4*)&src[(size_t)(k0 + rr) * DT + n0 + c];
      Ts[rr][c + 0] = v.x; Ts[rr][c + 1] = v.y;
      Ts[rr][c + 2] = v.z; Ts[rr][c + 3] = v.w;
    }
    __syncthreads();
#pragma unroll
    for (int i = 0; i < 2; i++) {
      int cid = t + i * 256;          // 512 chunks of 8
      int nr = cid >> 3, kc = cid & 7;
      union { uint4 u; short s2[8]; } pk;
#pragma unroll
      for (int j = 0; j < 8; j++) pk.s2[j] = f2b(Ts[kc * 8 + j][nr]);
      *(uint4*)&dst[(size_t)(n0 + nr) * DT + k0 + kc * 8] = pk.u;
    }
  } else if (bid < 1488) {
    // ---------------- ln_s branch
    const int row = bid - 720;
    const float* x = s + row * DT;
    float v0 = x[t], v1 = x[t + 256], v2 = x[t + 512];
    float sum = v0 + v1 + v2;
    float sq = v0 * v0 + v1 * v1 + v2 * v2;
#pragma unroll
    for (int off = 32; off; off >>= 1) {
      sum += __shfl_xor(sum, off);
      sq += __shfl_xor(sq, off);
    }
    __shared__ float ls[4], lq[4], stats[2];
    const int wid = t >> 6;
    if ((t & 63) == 0) { ls[wid] = sum; lq[wid] = sq; }
    __syncthreads();
    if (t == 0) {
      float S = ls[0] + ls[1] + ls[2] + ls[3];
      float Q = lq[0] + lq[1] + lq[2] + lq[3];
      float mu = S * (1.f / DT);
      float var = Q * (1.f / DT) - mu * mu;
      stats[0] = mu;
      stats[1] = rsqrtf(var + LN_EPS);
    }
    __syncthreads();
    const float mu = stats[0], rs = stats[1];
    short* y = snb + row * DT;
    y[t] = f2b((v0 - mu) * rs * nsw[t] + nsb[t]);
    y[t + 256] = f2b((v1 - mu) * rs * nsw[t + 256] + nsb[t + 256]);
    y[t + 512] = f2b((v2 - mu) * rs * nsw[t + 512] + nsb[t + 512]);
  } else {
    // ---------------- zsetup branch
    __shared__ float sm[ZDT * HT];     // w1[c][h] = znw[c] * zw[c][h]
#pragma unroll
    for (int i = 0; i < 8; i++) {
      int idx = t * 8 + i;
      int c = idx >> 4;
      sm[idx] = znw[c] * zw[idx];
    }
    __syncthreads();
#pragma unroll
    for (int i = 0; i < 8; i++) {
      int idx = t * 8 + i;
      int c = idx >> 4, h = idx & 15;
      float v = sm[idx];
      short hi = f2b(v);
      w1th[h * ZDT + c] = hi;                 // W^T hi (bf16)
      w1tl[h * ZDT + c] = f2b(v - b2f(hi));   // W^T lo residual (bf16)
    }
    if (t < HT) {
      float s1 = 0.f, s2 = 0.f;
      for (int c = 0; c < ZDT; c++) s1 += sm[c * HT + t];
      wcs[t] = s1;                            // column sums of w1
      for (int c = 0; c < ZDT; c++) s2 += znb[c] * zw[c * HT + t];
      bh[t] = s2;                             // folded LN bias term
    }
  }
}

// ---------------------------------------------------------------------------
// fused  proj (blocks 0..143)  ||  zbias (blocks 144..2447)
// Data-independent: proj needs {snb, wt} (setup), zbias needs {w1th..bh}
// (zsetup). proj blocks dispatch first, finish in ~15 us while the HBM-bound
// zbias stream runs behind them -> proj's serial time + one launch gap hidden.
// LDS overlaid in one 36.9 KB arena (proj: As+Bs shorts; zbias: 32 KB Zs).
// Both branch bodies byte-identical to round-6's separate kernels.
// ---------------------------------------------------------------------------
__global__ __launch_bounds__(256) void zbias_proj_kernel(
    const short* __restrict__ snb, const short* __restrict__ wt,
    const float* __restrict__ qbias, short* __restrict__ qb,
    short* __restrict__ kb, short* __restrict__ vT, short* __restrict__ gb,
    const float* __restrict__ z, const short* __restrict__ w1th,
    const short* __restrict__ w1tl, const float* __restrict__ wcs,
    const float* __restrict__ bh, short* __restrict__ biasb) {
  __shared__ __align__(16) char smem[2 * 128 * KP * 2];  // 36864 B arena
  const int bid = blockIdx.x;
  const int t = threadIdx.x;
  const int w = t >> 6, l = t & 63;
  const int lane16 = l & 15, quad = l >> 4;
  if (bid < 144) {
    // ---------------- proj branch (was grid 6x6x4: x=N0, y=M0, z=which)
    short* As = (short*)smem;
    short* Bs = (short*)(smem + 128 * KP * 2);
    const int which = bid / 36;
    const int rem = bid % 36;
    const int N0 = (rem % 6) * 128;
    const int M0 = (rem / 6) * 128;
    const short* W = wt + (size_t)which * NN;
    const int wm = (w >> 1) * 64, wn = (w & 1) * 64;
    ffrag acc[4][4] = {};
    const int srow = t >> 3, skc = t & 7;
    for (int k0 = 0; k0 < DT; k0 += 64) {
      uint4 av[4], bv[4];
#pragma unroll
      for (int i = 0; i < 4; i++) {
        int row = srow + i * 32;
        av[i] = *(const uint4*)&snb[(size_t)(M0 + row) * DT + k0 + skc * 8];
        bv[i] = *(const uint4*)&W[(size_t)(N0 + row) * DT + k0 + skc * 8];
      }
      __syncthreads();
#pragma unroll
      for (int i = 0; i < 4; i++) {
        int row = srow + i * 32;
        *(uint4*)&As[row * KP + skc * 8] = av[i];
        *(uint4*)&Bs[row * KP + skc * 8] = bv[i];
      }
      __syncthreads();
#pragma unroll
      for (int ks = 0; ks < 2; ks++) {
        bfrag a[4], b[4];
#pragma unroll
        for (int i = 0; i < 4; i++)
          a[i] = *(const bfrag*)&As[(wm + i * 16 + lane16) * KP + ks * 32 + quad * 8];
#pragma unroll
        for (int j = 0; j < 4; j++)
          b[j] = *(const bfrag*)&Bs[(wn + j * 16 + lane16) * KP + ks * 32 + quad * 8];
#pragma unroll
        for (int i = 0; i < 4; i++)
#pragma unroll
          for (int j = 0; j < 4; j++) acc[i][j] = MFMA16(a[i], b[j], acc[i][j]);
      }
      __syncthreads();
    }
#pragma unroll
    for (int i = 0; i < 4; i++) {
#pragma unroll
      for (int j = 0; j < 4; j++) {
        int n = N0 + wn + j * 16 + lane16;
#pragma unroll
        for (int r = 0; r < 4; r++) {
          int m = M0 + wm + i * 16 + quad * 4 + r;
          float v = acc[i][j][r];
          if (which == 0) {
            qb[(size_t)m * DT + n] = f2b(v + qbias[n]);
          } else if (which == 1) {
            kb[(size_t)m * DT + n] = f2b(v);
          } else if (which == 2) {
            vT[(size_t)n * NT + m] = f2b(v);   // [h*48+d][seq] for AV B-op
          } else {
            gb[(size_t)m * DT + n] = f2b(1.f / (1.f + __expf(-v)));
          }
        }
      }
    }
  } else {
    // ---------------- zbias branch (byte-identical to round-6 zbias_kernel)
    f4* Zs = (f4*)smem;                 // 32 KB of the arena
    f4* zs = Zs + w * 512;              // per-wave 8 KB slice
    const bfrag wh0 = *(const bfrag*)&w1th[lane16 * ZDT + 0 + quad * 8];
    const bfrag wh1 = *(const bfrag*)&w1th[lane16 * ZDT + 32 + quad * 8];
    const bfrag wh2 = *(const bfrag*)&w1th[lane16 * ZDT + 64 + quad * 8];
    const bfrag wh3 = *(const bfrag*)&w1th[lane16 * ZDT + 96 + quad * 8];
    const bfrag wl0 = *(const bfrag*)&w1tl[lane16 * ZDT + 0 + quad * 8];
    const bfrag wl1 = *(const bfrag*)&w1tl[lane16 * ZDT + 32 + quad * 8];
    const bfrag wl2 = *(const bfrag*)&w1tl[lane16 * ZDT + 64 + quad * 8];
    const bfrag wl3 = *(const bfrag*)&w1tl[lane16 * ZDT + 96 + quad * 8];
    const float wcs_h = wcs[lane16];
    const float bh_h = bh[lane16];
    const int row_base0 = (bid - 144) * 256 + w * 64;
    const int lh = l >> 5, lc = l & 31;           // write-side
    const int rsw = lane16 * 32, rx = lane16 & 7; // read-side
#pragma unroll
    for (int it = 0; it < 4; it++) {
      const int rbase = row_base0 + it * 16;
      const f4* ztile = (const f4*)&z[(size_t)rbase * ZDT];
      const f4 g0 = __builtin_nontemporal_load(ztile + 0 * 64 + l);
      const f4 g1 = __builtin_nontemporal_load(ztile + 1 * 64 + l);
      const f4 g2 = __builtin_nontemporal_load(ztile + 2 * 64 + l);
      const f4 g3 = __builtin_nontemporal_load(ztile + 3 * 64 + l);
      const f4 g4 = __builtin_nontemporal_load(ztile + 4 * 64 + l);
      const f4 g5 = __builtin_nontemporal_load(ztile + 5 * 64 + l);
      const f4 g6 = __builtin_nontemporal_load(ztile + 6 * 64 + l);
      const f4 g7 = __builtin_nontemporal_load(ztile + 7 * 64 + l);
      zs[(0 * 2 + lh) * 32 + (lc ^ ((0 * 2 + lh) & 7))] = g0;
      zs[(1 * 2 + lh) * 32 + (lc ^ ((1 * 2 + lh) & 7))] = g1;
      zs[(2 * 2 + lh) * 32 + (lc ^ ((2 * 2 + lh) & 7))] = g2;
      zs[(3 * 2 + lh) * 32 + (lc ^ ((3 * 2 + lh) & 7))] = g3;
      zs[(4 * 2 + lh) * 32 + (lc ^ ((4 * 2 + lh) & 7))] = g4;
      zs[(5 * 2 + lh) * 32 + (lc ^ ((5 * 2 + lh) & 7))] = g5;
      zs[(6 * 2 + lh) * 32 + (lc ^ ((6 * 2 + lh) & 7))] = g6;
      zs[(7 * 2 + lh) * 32 + (lc ^ ((7 * 2 + lh) & 7))] = g7;
      const f4 a0 = zs[rsw + ((2 * quad + 0) ^ rx)];
      const f4 b0 = zs[rsw + ((2 * quad + 1) ^ rx)];
      const f4 a1 = zs[rsw + ((2 * quad + 8) ^ rx)];
      const f4 b1 = zs[rsw + ((2 * quad + 9) ^ rx)];
      const f4 a2 = zs[rsw + ((2 * quad + 16) ^ rx)];
      const f4 b2 = zs[rsw + ((2 * quad + 17) ^ rx)];
      const f4 a3 = zs[rsw + ((2 * quad + 24) ^ rx)];
      const f4 b3 = zs[rsw + ((2 * quad + 25) ^ rx)];
      float sum = ((s4v(a0) + s4v(b0)) + (s4v(a1) + s4v(b1))) +
                  ((s4v(a2) + s4v(b2)) + (s4v(a3) + s4v(b3)));
      float sq = ((q4v(a0) + q4v(b0)) + (q4v(a1) + q4v(b1))) +
                 ((q4v(a2) + q4v(b2)) + (q4v(a3) + q4v(b3)));
      sum += __shfl_xor(sum, 16); sq += __shfl_xor(sq, 16);
      sum += __shfl_xor(sum, 32); sq += __shfl_xor(sq, 32);
      const bfrag xh0 = {hi16(a0.x), hi16(a0.y), hi16(a0.z), hi16(a0.w),
                         hi16(b0.x), hi16(b0.y), hi16(b0.z), hi16(b0.w)};
      const bfrag xl0 = {lo16(a0.x), lo16(a0.y), lo16(a0.z), lo16(a0.w),
                         lo16(b0.x), lo16(b0.y), lo16(b0.z), lo16(b0.w)};
      const bfrag xh1 = {hi16(a1.x), hi16(a1.y), hi16(a1.z), hi16(a1.w),
                         hi16(b1.x), hi16(b1.y), hi16(b1.z), hi16(b1.w)};
      const bfrag xl1 = {lo16(a1.x), lo16(a1.y), lo16(a1.z), lo16(a1.w),
                         lo16(b1.x), lo16(b1.y), lo16(b1.z), lo16(b1.w)};
      const bfrag xh2 = {hi16(a2.x), hi16(a2.y), hi16(a2.z), hi16(a2.w),
                         hi16(b2.x), hi16(b2.y), hi16(b2.z), hi16(b2.w)};
      const bfrag xl2 = {lo16(a2.x), lo16(a2.y), lo16(a2.z), lo16(a2.w),
                         lo16(b2.x), lo16(b2.y), lo16(b2.z), lo16(b2.w)};
      const bfrag xh3 = {hi16(a3.x), hi16(a3.y), hi16(a3.z), hi16(a3.w),
                         hi16(b3.x), hi16(b3.y), hi16(b3.z), hi16(b3.w)};
      const bfrag xl3 = {lo16(a3.x), lo16(a3.y), lo16(a3.z), lo16(a3.w),
                         lo16(b3.x), lo16(b3.y), lo16(b3.z), lo16(b3.w)};
      ffrag accA = {0.f, 0.f, 0.f, 0.f};   // xh * Wh
      ffrag accB = {0.f, 0.f, 0.f, 0.f};   // xl * Wh
      ffrag accC = {0.f, 0.f, 0.f, 0.f};   // xh * Wl
      accA = MFMA16(xh0, wh0, accA);
      accB = MFMA16(xl0, wh0, accB);
      accC = MFMA16(xh0, wl0, accC);
      accA = MFMA16(xh1, wh1, accA);
      accB = MFMA16(xl1, wh1, accB);
      accC = MFMA16(xh1, wl1, accC);
      accA = MFMA16(xh2, wh2, accA);
      accB = MFMA16(xl2, wh2, accB);
      accC = MFMA16(xh2, wl2, accC);
      accA = MFMA16(xh3, wh3, accA);
      accB = MFMA16(xl3, wh3, accB);
      accC = MFMA16(xh3, wl3, accC);
      union { uint2 u; short s2[4]; } pk;
#pragma unroll
      for (int r = 0; r < 4; r++) {
        float rsum = __shfl(sum, quad * 4 + r);
        float rsq = __shfl(sq, quad * 4 + r);
        float mu = rsum * (1.f / 128.f);
        float rs = rsqrtf(rsq * (1.f / 128.f) - mu * mu + LN_EPS);
        float av = (accA[r] + accB[r]) + accC[r];
        pk.s2[r] = f2b(rs * (av - mu * wcs_h) + bh_h);
      }
      *(uint2*)&biasb[(size_t)lane16 * NN + rbase + quad * 4] = pk.u;
    }
  }
}

// ------- fused attention: S=QK^T*scale+bias, online softmax, O=PV
// grid (12 q-tiles of 64, 16 heads); 4 waves, wave w owns q-rows w*16..+16
__global__ __launch_bounds__(256) void attn_kernel(
    const short* __restrict__ qb, const short* __restrict__ kb,
    const short* __restrict__ vT, const short* __restrict__ biasb,
    float* __restrict__ oX) {
  __shared__ short Ks[128 * 48];       // [kpos][d]
  __shared__ short Vs[48 * 136];       // [d][kpos+8 pad]
  __shared__ short Ps[4][16 * 136];    // per-wave private P slice
  const int t = threadIdx.x;
  const int h = blockIdx.y;
  const int q0 = blockIdx.x * 64;
  const int w = t >> 6, l = t & 63;
  const int lane16 = l & 15, quad = l >> 4;
  const int qrow = q0 + w * 16 + lane16;
  bfrag a_q0 = *(const bfrag*)&qb[(size_t)qrow * DT + h * HDT + quad * 8];
  bfrag a_q1 = {0, 0, 0, 0, 0, 0, 0, 0};   // k 48..63 zero-padded
  if (quad < 2)
    a_q1 = *(const bfrag*)&qb[(size_t)qrow * DT + h * HDT + 32 + quad * 8];
  const int koff1 = (quad < 2) ? (32 + quad * 8) : 0;
  ffrag acc_o[3] = {};
  float m_run[4] = {-1e30f, -1e30f, -1e30f, -1e30f};
  float l_run[4] = {};
  const size_t bias_base =
      (size_t)h * NN + (size_t)(q0 + w * 16 + quad * 4) * NT + lane16;
  for (int kt = 0; kt < 6; kt++) {
    const int k0 = kt * 128;
    uint4 kv[3], vv[3];
#pragma unroll
    for (int i = 0; i < 3; i++) {
      int cid = t + i * 256;
      int kr = cid / 6, kc = cid % 6;
      kv[i] = *(const uint4*)&kb[(size_t)(k0 + kr) * DT + h * HDT + kc * 8];
      int vr = cid >> 4, vc = cid & 15;
      vv[i] = *(const uint4*)&vT[((size_t)h * HDT + vr) * NT + k0 + vc * 8];
    }
    short bias_s[8][4];
#pragma unroll
    for (int j = 0; j < 8; j++)
#pragma unroll
      for (int r = 0; r < 4; r++)
        bias_s[j][r] = biasb[bias_base + (size_t)r * NT + k0 + j * 16];
    __syncthreads();
#pragma unroll
    for (int i = 0; i < 3; i++) {
      int cid = t + i * 256;
      int kr = cid / 6, kc = cid % 6;
      *(uint4*)&Ks[kr * 48 + kc * 8] = kv[i];
      int vr = cid >> 4, vc = cid & 15;
      *(uint4*)&Vs[vr * 136 + vc * 8] = vv[i];
    }
    __syncthreads();
    // S = Q K^T   (8 n-tiles x 2 k-steps)
    ffrag sc[8];
#pragma unroll
    for (int j = 0; j < 8; j++) {
      ffrag zf = {0.f, 0.f, 0.f, 0.f};
      bfrag b0 = *(const bfrag*)&Ks[(j * 16 + lane16) * 48 + quad * 8];
      bfrag b1 = *(const bfrag*)&Ks[(j * 16 + lane16) * 48 + koff1];
      zf = MFMA16(a_q0, b0, zf);
      sc[j] = MFMA16(a_q1, b1, zf);
    }
    // logits + online softmax (C layout: col=lane16, row=quad*4+r)
    float li[8][4];
#pragma unroll
    for (int j = 0; j < 8; j++)
#pragma unroll
      for (int r = 0; r < 4; r++)
        li[j][r] = sc[j][r] * SCALE + b2f(bias_s[j][r]);
    float alpha[4];
#pragma unroll
    for (int r = 0; r < 4; r++) {
      float m = li[0][r];
#pragma unroll
      for (int j = 1; j < 8; j++) m = fmaxf(m, li[j][r]);
#pragma unroll
      for (int k = 1; k <= 8; k <<= 1) m = fmaxf(m, __shfl_xor(m, k));
      float mn = fmaxf(m_run[r], m);
      alpha[r] = __expf(m_run[r] - mn);
      m_run[r] = mn;
    }
#pragma unroll
    for (int j = 0; j < 8; j++)
#pragma unroll
      for (int r = 0; r < 4; r++) li[j][r] = __expf(li[j][r] - m_run[r]);
#pragma unroll
    for (int r = 0; r < 4; r++) {
      float ssum = li[0][r];
#pragma unroll
      for (int j = 1; j < 8; j++) ssum += li[j][r];
#pragma unroll
      for (int k = 1; k <= 8; k <<= 1) ssum += __shfl_xor(ssum, k);
      l_run[r] = l_run[r] * alpha[r] + ssum;
    }
#pragma unroll
    for (int dt = 0; dt < 3; dt++)
#pragma unroll
      for (int r = 0; r < 4; r++) acc_o[dt][r] *= alpha[r];
#pragma unroll
    for (int j = 0; j < 8; j++)
#pragma unroll
      for (int r = 0; r < 4; r++)
        Ps[w][(quad * 4 + r) * 136 + j * 16 + lane16] = f2b(li[j][r]);
    // O += P V   (3 d-tiles x 4 k-steps)
#pragma unroll
    for (int ks = 0; ks < 4; ks++) {
      bfrag ap = *(const bfrag*)&Ps[w][lane16 * 136 + ks * 32 + quad * 8];
#pragma unroll
      for (int dt = 0; dt < 3; dt++) {
        bfrag bv = *(const bfrag*)&Vs[(dt * 16 + lane16) * 136 + ks * 32 + quad * 8];
        acc_o[dt] = MFMA16(ap, bv, acc_o[dt]);
      }
    }
  }
  float inv[4];
#pragma unroll
  for (int r = 0; r < 4; r++) inv[r] = 1.f / l_run[r];
#pragma unroll
  for (int dt = 0; dt < 3; dt++)
#pragma unroll
    for (int r = 0; r < 4; r++)
      oX[(size_t)(q0 + w * 16 + quad * 4 + r) * DT + h * HDT + dt * 16 + lane16] =
          acc_o[dt][r] * inv[r];
}

// ---------------------------- out = (o .* g) @ o_w via bf16 MFMA, 64x64 tiles
__global__ __launch_bounds__(256) void outproj_kernel(
    const float* __restrict__ oX, const short* __restrict__ gb,
    const short* __restrict__ owt, float* __restrict__ out) {
  __shared__ short As[64 * KP];
  __shared__ short Bs[64 * KP];
  const int t = threadIdx.x;
  const int N0 = blockIdx.x * 64;
  const int M0 = blockIdx.y * 64;
  const int w = t >> 6, l = t & 63;
  const int wm = (w >> 1) * 32, wn = (w & 1) * 32;
  const int lane16 = l & 15, quad = l >> 4;
  ffrag acc[2][2] = {};
  const int srow = t >> 2;          // 0..63
  const int sc = (t & 3) * 16;      // elem offset 0/16/32/48
  for (int k0 = 0; k0 < DT; k0 += 64) {
    uint4 apk[2], bvv[2];
    const float* op = &oX[(size_t)(M0 + srow) * DT + k0 + sc];
    const short* gp = &gb[(size_t)(M0 + srow) * DT + k0 + sc];
    const short* bp = &owt[(size_t)(N0 + srow) * DT + k0 + sc];
#pragma unroll
    for (int i = 0; i < 2; i++) {
      float4 o0 = *(const float4*)&op[i * 8 + 0];
      float4 o1 = *(const float4*)&op[i * 8 + 4];
      union { uint4 u; short s2[8]; } gv;
      gv.u = *(const uint4*)&gp[i * 8];
      union { uint4 u; short s2[8]; } pk;
      float go[8] = {o0.x, o0.y, o0.z, o0.w, o1.x, o1.y, o1.z, o1.w};
#pragma unroll
      for (int jj = 0; jj < 8; jj++) pk.s2[jj] = f2b(go[jj] * b2f(gv.s2[jj]));
      apk[i] = pk.u;
      bvv[i] = *(const uint4*)&bp[i * 8];
    }
    __syncthreads();
    *(uint4*)&As[srow * KP + sc] = apk[0];
    *(uint4*)&As[srow * KP + sc + 8] = apk[1];
    *(uint4*)&Bs[srow * KP + sc] = bvv[0];
    *(uint4*)&Bs[srow * KP + sc + 8] = bvv[1];
    __syncthreads();
#pragma unroll
    for (int ks = 0; ks < 2; ks++) {
      bfrag a[2], b[2];
#pragma unroll
      for (int i = 0; i < 2; i++)
        a[i] = *(const bfrag*)&As[(wm + i * 16 + lane16) * KP + ks * 32 + quad * 8];
#pragma unroll
      for (int j = 0; j < 2; j++)
        b[j] = *(const bfrag*)&Bs[(wn + j * 16 + lane16) * KP + ks * 32 + quad * 8];
#pragma unroll
      for (int i = 0; i < 2; i++)
#pragma unroll
        for (int j = 0; j < 2; j++) acc[i][j] = MFMA16(a[i], b[j], acc[i][j]);
    }
  }
#pragma unroll
  for (int i = 0; i < 2; i++)
#pragma unroll
    for (int j = 0; j < 2; j++) {
      int n = N0 + wn + j * 16 + lane16;
#pragma unroll
      for (int r = 0; r < 4; r++) {
        int m = M0 + wm + i * 16 + quad * 4 + r;
        out[(size_t)m * DT + n] = acc[i][j][r];
      }
    }
}

extern "C" void kernel_launch(void* const* d_in, const int* in_sizes, int n_in,
                              void* d_out, int out_size, void* d_ws,
                              size_t ws_size, hipStream_t stream) {
  const float* s = (const float*)d_in[0];
  const float* z = (const float*)d_in[1];
  const float* nsw = (const float*)d_in[2];
  const float* nsb = (const float*)d_in[3];
  const float* qw = (const float*)d_in[4];
  const float* qbias = (const float*)d_in[5];
  const float* kw = (const float*)d_in[6];
  const float* vw = (const float*)d_in[7];
  const float* gw = (const float*)d_in[8];
  const float* znw = (const float*)d_in[9];
  const float* znb = (const float*)d_in[10];
  const float* zww = (const float*)d_in[11];
  const float* ow = (const float*)d_in[12];
  float* out = (float*)d_out;
  char* W = (char*)d_ws;

  short* biasb = (short*)W;                        // 18,874,368 B
  short* snb = (short*)(W + 18874368);             // 1,179,648 B
  short* qb = (short*)(W + 20054016);
  short* kb = (short*)(W + 21233664);
  short* gb = (short*)(W + 22413312);
  short* vT = (short*)(W + 23592960);
  short* wt = (short*)(W + 24772608);              // 5 x 1,179,648 B
  float* oX = (float*)(W + 30670848);              // 2,359,296 B
  short* w1th = (short*)(W + 33030144);            // 4096 B
  short* w1tl = (short*)(W + 33034240);            // 4096 B
  float* wcs = (float*)(W + 33038336);             // 64 B
  float* bh = (float*)(W + 33038400);              // 64 B

  // setup -> (proj || zbias) -> attn -> outproj   (4 launches)
  setup_kernel<<<1489, 256, 0, stream>>>(s, nsw, nsb, snb, qw, kw, vw, gw, ow,
                                         wt, znw, znb, zww, w1th, w1tl, wcs,
                                         bh);
  zbias_proj_kernel<<<2448, 256, 0, stream>>>(snb, wt, qbias, qb, kb, vT, gb,
                                              z, w1th, w1tl, wcs, bh, biasb);
  attn_kernel<<<dim3(12, 16), 256, 0, stream>>>(qb, kb, vT, biasb, oX);
  outproj_kernel<<<dim3(12, 12), 256, 0, stream>>>(oX, gb, wt + 4 * (size_t)NN,
                                                   out);
}